// Round 1
// baseline (1160.426 us; speedup 1.0000x reference)
//
#include <hip/hip_runtime.h>
#include <math.h>

#define WAVE 64

__device__ __forceinline__ float lrelu(float x){ return x > 0.0f ? x : 0.2f*x; }

// ---------- precompute ----------

// wvec[l][k] = sum_c conv_We[l][k][c] * att_edge[l][c]
__global__ void k_wvec(const float* __restrict__ We, const float* __restrict__ atte,
                       float* __restrict__ wvec, int L, int D, int H){
    int t = blockIdx.x*blockDim.x + threadIdx.x;
    if(t >= L*D) return;
    int l = t / D, k = t % D;
    const float* w = We + ((size_t)l*D + k)*H;
    const float* a = atte + l*H;
    float s = 0.f;
    for(int c=0;c<H;c++) s += w[c]*a[c];
    wvec[t] = s;
}

__global__ void k_gather_x(const int* __restrict__ xidx, const float* __restrict__ emb,
                           float* __restrict__ x, int n){
    int i = blockIdx.x*256 + threadIdx.x;
    if(i >= n*128) return;
    x[i] = emb[xidx[i>>7]*128 + (i&127)];
}

__global__ void k_count(const int* __restrict__ dst, int* __restrict__ cnt, int E){
    int e = blockIdx.x*256 + threadIdx.x;
    if(e < E) atomicAdd(&cnt[dst[e]], 1);
}

// exclusive prefix sum over n counts -> rowptr[0..n]
__global__ __launch_bounds__(1024) void k_scan(const int* __restrict__ cnt, int* __restrict__ rowptr, int n){
    __shared__ int sh[1024];
    __shared__ int carry;
    int tid = threadIdx.x;
    if(tid==0){ carry = 0; rowptr[0] = 0; }
    __syncthreads();
    for(int base=0; base<n; base+=1024){
        int i = base + tid;
        int v = (i<n) ? cnt[i] : 0;
        sh[tid] = v; __syncthreads();
        for(int off=1; off<1024; off<<=1){
            int t = (tid>=off) ? sh[tid-off] : 0;
            __syncthreads();
            sh[tid] += t;
            __syncthreads();
        }
        int c = carry;
        if(i<n) rowptr[i+1] = c + sh[tid];
        __syncthreads();
        if(tid==0) carry = c + sh[1023];
        __syncthreads();
    }
}

__global__ void k_scatter(const int* __restrict__ dst, const int* __restrict__ rowptr,
                          int* __restrict__ cnt2, int* __restrict__ eid, int E){
    int e = blockIdx.x*256 + threadIdx.x;
    if(e >= E) return;
    int d = dst[e];
    int p = rowptr[d] + atomicAdd(&cnt2[d], 1);
    eid[p] = e;
}

// deterministic order: sort each node's edge list by original edge id
__global__ void k_sort(const int* __restrict__ rowptr, int* __restrict__ eid, int n){
    int v = blockIdx.x*256 + threadIdx.x;
    if(v >= n) return;
    int b = rowptr[v], e = rowptr[v+1];
    for(int i=b+1; i<e; i++){
        int key = eid[i]; int j = i-1;
        while(j>=b && eid[j] > key){ eid[j+1] = eid[j]; j--; }
        eid[j+1] = key;
    }
}

// per CSR slot: csr_src and a_e for all 6 layers
__global__ __launch_bounds__(256) void k_ae(const int* __restrict__ eid, const int* __restrict__ src,
                     const int* __restrict__ eattr, const float* __restrict__ emb,
                     const float* __restrict__ wvec, int* __restrict__ csrsrc,
                     float* __restrict__ ae, int E){
    __shared__ float wv[6*128];
    for(int i=threadIdx.x; i<6*128; i+=256) wv[i] = wvec[i];
    __syncthreads();
    int p = blockIdx.x*256 + threadIdx.x;
    if(p >= E) return;
    int e = eid[p];
    csrsrc[p] = src[e];
    const float4* er = (const float4*)(emb + (size_t)eattr[e]*128);
    float acc[6] = {0,0,0,0,0,0};
    for(int k=0;k<32;k++){
        float4 v = er[k];
        #pragma unroll
        for(int l=0;l<6;l++){
            const float* w = wv + l*128 + k*4;
            acc[l] += v.x*w[0] + v.y*w[1] + v.z*w[2] + v.w*w[3];
        }
    }
    #pragma unroll
    for(int l=0;l<6;l++) ae[(size_t)l*E + p] = acc[l];
}

// a_e for the self loop: mean of incoming a_e (deterministic sequential sum)
__global__ void k_aeloop(const int* __restrict__ rowptr, const float* __restrict__ ae,
                         float* __restrict__ ael, int n, int E){
    int v = blockIdx.x*256 + threadIdx.x;
    if(v >= n) return;
    int b = rowptr[v], e = rowptr[v+1];
    float dg = fmaxf((float)(e-b), 1.0f);
    #pragma unroll
    for(int l=0;l<6;l++){
        float s = 0.f;
        for(int p=b;p<e;p++) s += ae[(size_t)l*E + p];
        ael[(size_t)l*n + v] = s / dg;
    }
}

// ---------- per-layer ----------

// h = x @ W  (N,128)@(128,64); a_s = h@att_src; a_d = h@att_dst
__global__ __launch_bounds__(256) void k_h(const float* __restrict__ x, const float* __restrict__ W,
                    const float* __restrict__ atts, const float* __restrict__ attd,
                    float* __restrict__ h, float* __restrict__ as_, float* __restrict__ ad_, int n){
    __shared__ float Ws[128*64];
    for(int i=threadIdx.x; i<128*64; i+=256) Ws[i] = W[i];
    __syncthreads();
    int lane = threadIdx.x & 63, wid = threadIdx.x >> 6;
    float av = atts[lane], dv = attd[lane];
    for(int node = blockIdx.x*4 + wid; node < n; node += gridDim.x*4){
        const float* xr = x + (size_t)node*128;
        float acc = 0.f;
        #pragma unroll 8
        for(int k=0;k<128;k++) acc += xr[k]*Ws[k*64+lane];
        h[(size_t)node*64 + lane] = acc;
        float s = acc*av, d2 = acc*dv;
        #pragma unroll
        for(int off=32; off; off>>=1){ s += __shfl_xor(s,off,64); d2 += __shfl_xor(d2,off,64); }
        if(lane==0){ as_[node] = s; ad_[node] = d2; }
    }
}

// GAT aggregation: wave per node, online softmax over incoming edges + self loop
__global__ __launch_bounds__(256) void k_gat(const float* __restrict__ h, const float* __restrict__ as_,
                      const float* __restrict__ ad_, const float* __restrict__ ae,
                      const float* __restrict__ ael, const int* __restrict__ rowptr,
                      const int* __restrict__ csrsrc, const float* __restrict__ bias,
                      float* __restrict__ o, int n){
    int node = blockIdx.x*4 + (threadIdx.x>>6);
    if(node >= n) return;
    int lane = threadIdx.x & 63;
    int b = rowptr[node], e = rowptr[node+1];
    float asn = as_[node], adn = ad_[node];
    float ls = lrelu(asn + adn + ael[node]);
    float m = ls, d = 1.0f;                       // self loop: w = exp(0) = 1
    float acc = h[(size_t)node*64 + lane];        // * 1
    for(int j0=b; j0<e; j0+=64){
        int nj = min(64, e-j0);
        int sj = 0; float lg = -1e30f;
        if(lane < nj){
            sj = csrsrc[j0+lane];
            lg = lrelu(as_[sj] + adn + ae[j0+lane]);
        }
        float cm = lg;
        #pragma unroll
        for(int off=32; off; off>>=1) cm = fmaxf(cm, __shfl_xor(cm,off,64));
        float nm = fmaxf(m, cm);
        float w = (lane<nj) ? expf(lg-nm) : 0.0f;
        float scale = expf(m-nm);
        float ws = w;
        #pragma unroll
        for(int off=32; off; off>>=1) ws += __shfl_xor(ws,off,64);
        d = d*scale + ws;
        acc *= scale;
        for(int j=0;j<nj;j++){
            float wj = __shfl(w, j, 64);
            int s = __shfl(sj, j, 64);
            acc += wj * h[(size_t)s*64 + lane];
        }
        m = nm;
    }
    o[(size_t)node*64 + lane] = acc/d + bias[lane];
}

// MLP3 (64->64->64->128) + JKN running-best update
__global__ __launch_bounds__(256) void k_mlp(const float* __restrict__ o,
                      const float* __restrict__ W1, const float* __restrict__ b1,
                      const float* __restrict__ W2, const float* __restrict__ b2,
                      const float* __restrict__ W3, const float* __restrict__ b3,
                      float* __restrict__ xn, float* __restrict__ bestF, float* __restrict__ bestMs,
                      int layer, int n){
    __shared__ float W1s[64*64], W2s[64*64], W3s[64*128];
    for(int i=threadIdx.x; i<4096; i+=256){ W1s[i]=W1[i]; W2s[i]=W2[i]; }
    for(int i=threadIdx.x; i<8192; i+=256) W3s[i]=W3[i];
    __syncthreads();
    int lane = threadIdx.x & 63, wid = threadIdx.x >> 6;
    float b1l=b1[lane], b2l=b2[lane], b3a=b3[lane], b3b=b3[lane+64];
    for(int node = blockIdx.x*4 + wid; node < n; node += gridDim.x*4){
        const float* orow = o + (size_t)node*64;
        float t1 = b1l;
        #pragma unroll 8
        for(int k=0;k<64;k++) t1 += orow[k]*W1s[k*64+lane];
        t1 = fmaxf(t1, 0.f);
        float t2 = b2l;
        #pragma unroll 8
        for(int k=0;k<64;k++) t2 += __shfl(t1,k,64)*W2s[k*64+lane];
        t2 = fmaxf(t2, 0.f);
        float v0 = b3a, v1 = b3b;
        #pragma unroll 8
        for(int k=0;k<64;k++){ float t = __shfl(t2,k,64); v0 += t*W3s[k*128+lane]; v1 += t*W3s[k*128+lane+64]; }
        xn[(size_t)node*128 + lane] = v0;
        xn[(size_t)node*128 + lane + 64] = v1;
        float ms = v0*v0 + v1*v1;
        #pragma unroll
        for(int off=32; off; off>>=1) ms += __shfl_xor(ms,off,64);
        bool upd = (layer==0) || (ms > bestMs[node]);   // strict >: argmax first-occurrence
        if(upd){
            bestF[(size_t)node*128 + lane] = v0;
            bestF[(size_t)node*128 + lane + 64] = v1;
            if(lane==0) bestMs[node] = ms;
        }
    }
}

// ---------- pooling ----------

__global__ __launch_bounds__(256) void k_pool1(const float* __restrict__ F,
                      const float* __restrict__ g1W1, const float* __restrict__ g1b1,
                      const float* __restrict__ g1W2, const float* __restrict__ g1b2,
                      const float* __restrict__ g2W1, const float* __restrict__ g2b1,
                      const float* __restrict__ g2W2, const float* __restrict__ g2b2,
                      float* __restrict__ h1, float* __restrict__ h2, int n){
    __shared__ float A[128*64], B[128*64], C[64*128], w2s[64];
    for(int i=threadIdx.x; i<8192; i+=256){ A[i]=g1W1[i]; B[i]=g2W1[i]; C[i]=g2W2[i]; }
    if(threadIdx.x<64) w2s[threadIdx.x] = g1W2[threadIdx.x];
    __syncthreads();
    int lane = threadIdx.x & 63, wid = threadIdx.x >> 6;
    float b1a=g1b1[lane], b2v=g1b2[0], b1b=g2b1[lane], b2a=g2b2[lane], b2b=g2b2[lane+64];
    for(int node = blockIdx.x*4 + wid; node < n; node += gridDim.x*4){
        const float* f = F + (size_t)node*128;
        float p1=b1a, p2=b1b;
        #pragma unroll 4
        for(int k=0;k<128;k++){ float fv=f[k]; p1 += fv*A[k*64+lane]; p2 += fv*B[k*64+lane]; }
        p1 = fmaxf(p1,0.f); p2 = fmaxf(p2,0.f);
        float s = p1*w2s[lane];
        #pragma unroll
        for(int off=32; off; off>>=1) s += __shfl_xor(s,off,64);
        if(lane==0) h1[node] = s + b2v;
        float v0=b2a, v1=b2b;
        #pragma unroll 8
        for(int k=0;k<64;k++){ float t=__shfl(p2,k,64); v0 += t*C[k*128+lane]; v1 += t*C[k*128+lane+64]; }
        h2[(size_t)node*128 + lane] = v0;
        h2[(size_t)node*128 + lane + 64] = v1;
    }
}

__global__ __launch_bounds__(128) void k_pool2(const float* __restrict__ h1, const float* __restrict__ h2,
                      float* __restrict__ wbuf, float* __restrict__ hg, int n, int G){
    __shared__ float sh[128];
    int g = blockIdx.x, tid = threadIdx.x;
    int start = (g*n + G-1)/G, end = ((g+1)*n + G-1)/G;
    float lm = -1e30f;
    for(int i=start+tid; i<end; i+=128) lm = fmaxf(lm, h1[i]);
    sh[tid]=lm; __syncthreads();
    for(int off=64; off; off>>=1){ if(tid<off) sh[tid]=fmaxf(sh[tid],sh[tid+off]); __syncthreads(); }
    float m = sh[0]; __syncthreads();
    float lsum = 0.f;
    for(int i=start+tid; i<end; i+=128){ float w = expf(h1[i]-m); wbuf[i]=w; lsum+=w; }
    sh[tid]=lsum; __syncthreads();
    for(int off=64; off; off>>=1){ if(tid<off) sh[tid]+=sh[tid+off]; __syncthreads(); }
    float denom = sh[0];
    float acc = 0.f;
    for(int i=start; i<end; i++) acc += wbuf[i]*h2[(size_t)i*128 + tid];
    hg[g*128 + tid] = acc/denom/(float)(end-start);
}

__global__ __launch_bounds__(256) void k_final(const float* __restrict__ hg,
                      const float* __restrict__ pW1, const float* __restrict__ pb1,
                      const float* __restrict__ pW2, const float* __restrict__ pb2,
                      const float* __restrict__ pW3, const float* __restrict__ pb3,
                      float* __restrict__ out, int G){
    int lane = threadIdx.x & 63, wid = threadIdx.x >> 6;
    for(int g = wid; g < G; g += 4){
        const float* r = hg + g*128;
        float t1 = pb1[lane];
        for(int k=0;k<128;k++) t1 += r[k]*pW1[k*64+lane];
        t1 = fmaxf(t1,0.f);
        float t2 = pb2[lane];
        for(int k=0;k<64;k++) t2 += __shfl(t1,k,64)*pW2[k*64+lane];
        t2 = fmaxf(t2,0.f);
        float s = t2*pW3[lane];
        #pragma unroll
        for(int off=32; off; off>>=1) s += __shfl_xor(s,off,64);
        if(lane==0) out[g] = s + pb3[0];
    }
}

extern "C" void kernel_launch(void* const* d_in, const int* in_sizes, int n_in,
                              void* d_out, int out_size, void* d_ws, size_t ws_size,
                              hipStream_t stream){
    const int*   x_idx   = (const int*)  d_in[0];
    const int*   eindex  = (const int*)  d_in[1];
    const int*   eattr   = (const int*)  d_in[2];
    /* batch (d_in[3]) recomputed arithmetically */
    const float* emb     = (const float*)d_in[4];
    const float* conv_W  = (const float*)d_in[5];
    const float* conv_We = (const float*)d_in[6];
    const float* att_src = (const float*)d_in[7];
    const float* att_dst = (const float*)d_in[8];
    const float* att_edg = (const float*)d_in[9];
    const float* conv_b  = (const float*)d_in[10];
    const float* mW1 = (const float*)d_in[11]; const float* mb1 = (const float*)d_in[12];
    const float* mW2 = (const float*)d_in[13]; const float* mb2 = (const float*)d_in[14];
    const float* mW3 = (const float*)d_in[15]; const float* mb3 = (const float*)d_in[16];
    const float* g1W1= (const float*)d_in[17]; const float* g1b1= (const float*)d_in[18];
    const float* g1W2= (const float*)d_in[19]; const float* g1b2= (const float*)d_in[20];
    const float* g2W1= (const float*)d_in[21]; const float* g2b1= (const float*)d_in[22];
    const float* g2W2= (const float*)d_in[23]; const float* g2b2= (const float*)d_in[24];
    const float* pW1 = (const float*)d_in[25]; const float* pb1 = (const float*)d_in[26];
    const float* pW2 = (const float*)d_in[27]; const float* pb2 = (const float*)d_in[28];
    const float* pW3 = (const float*)d_in[29]; const float* pb3 = (const float*)d_in[30];

    const int N = in_sizes[0];
    const int E = in_sizes[2];
    const int G = out_size;          // 64
    const int* src = eindex;
    const int* dst = eindex + E;

    // workspace carve (256B aligned)
    char* p = (char*)d_ws;
    auto alloc = [&](size_t bytes)->void*{ void* r = (void*)p; p += (bytes + 255) & ~(size_t)255; return r; };
    float* xA     = (float*)alloc((size_t)N*128*4);
    float* xB     = (float*)alloc((size_t)N*128*4);
    float* bestF  = (float*)alloc((size_t)N*128*4);
    float* bestMs = (float*)alloc((size_t)N*4);
    float* h      = (float*)alloc((size_t)N*64*4);
    float* o      = (float*)alloc((size_t)N*64*4);
    float* as_    = (float*)alloc((size_t)N*4);
    float* ad_    = (float*)alloc((size_t)N*4);
    float* ae     = (float*)alloc((size_t)6*E*4);
    float* ael    = (float*)alloc((size_t)6*N*4);
    float* wvec   = (float*)alloc(6*128*4);
    float* h1     = (float*)alloc((size_t)N*4);
    float* hg     = (float*)alloc((size_t)G*128*4);
    int*   cnt    = (int*)  alloc((size_t)N*4);
    int*   cnt2   = (int*)  alloc((size_t)N*4);
    int*   rowptr = (int*)  alloc((size_t)(N+1)*4);
    int*   eid    = (int*)  alloc((size_t)E*4);
    int*   csrsrc = (int*)  alloc((size_t)E*4);

    hipMemsetAsync(cnt,  0, (size_t)N*4, stream);
    hipMemsetAsync(cnt2, 0, (size_t)N*4, stream);

    k_wvec<<<(6*128+255)/256, 256, 0, stream>>>(conv_We, att_edg, wvec, 6, 128, 64);
    k_gather_x<<<(N*128+255)/256, 256, 0, stream>>>(x_idx, emb, xA, N);
    k_count<<<(E+255)/256, 256, 0, stream>>>(dst, cnt, E);
    k_scan<<<1, 1024, 0, stream>>>(cnt, rowptr, N);
    k_scatter<<<(E+255)/256, 256, 0, stream>>>(dst, rowptr, cnt2, eid, E);
    k_sort<<<(N+255)/256, 256, 0, stream>>>(rowptr, eid, N);
    k_ae<<<(E+255)/256, 256, 0, stream>>>(eid, src, eattr, emb, wvec, csrsrc, ae, E);
    k_aeloop<<<(N+255)/256, 256, 0, stream>>>(rowptr, ae, ael, N, E);

    const float* xin = xA; float* xout = xB;
    for(int l=0; l<6; l++){
        k_h<<<512, 256, 0, stream>>>(xin, conv_W + (size_t)l*8192, att_src + l*64, att_dst + l*64, h, as_, ad_, N);
        k_gat<<<(N+3)/4, 256, 0, stream>>>(h, as_, ad_, ae + (size_t)l*E, ael + (size_t)l*N, rowptr, csrsrc, conv_b + l*64, o, N);
        k_mlp<<<512, 256, 0, stream>>>(o, mW1 + (size_t)l*4096, mb1 + l*64, mW2 + (size_t)l*4096, mb2 + l*64,
                                       mW3 + (size_t)l*8192, mb3 + l*128, xout, bestF, bestMs, l, N);
        float* t = xout; xout = (float*)xin; xin = t;
    }
    float* h2 = xout;   // free buffer after the layer loop

    k_pool1<<<512, 256, 0, stream>>>(bestF, g1W1, g1b1, g1W2, g1b2, g2W1, g2b1, g2W2, g2b2, h1, h2, N);
    k_pool2<<<G, 128, 0, stream>>>(h1, h2, as_, hg, N, G);
    k_final<<<1, 256, 0, stream>>>(hg, pW1, pb1, pW2, pb2, pW3, pb3, (float*)d_out, G);
}

// Round 2
// 725.860 us; speedup vs baseline: 1.5987x; 1.5987x over previous
//
#include <hip/hip_runtime.h>
#include <math.h>

__device__ __forceinline__ float lrelu(float x){ return x > 0.0f ? x : 0.2f*x; }
__device__ __forceinline__ float bcastf(float v, int l){
    return __int_as_float(__builtin_amdgcn_readlane(__float_as_int(v), l));
}

// ---------------- precompute ----------------

// wvec[l][k] = sum_c conv_We[l][k][c] * att_edge[l][c]
__global__ void k_wvec(const float* __restrict__ We, const float* __restrict__ atte,
                       float* __restrict__ wvec, int L, int D, int H){
    int t = blockIdx.x*blockDim.x + threadIdx.x;
    if(t >= L*D) return;
    int l = t / D, k = t % D;
    const float* w = We + ((size_t)l*D + k)*H;
    const float* a = atte + l*H;
    float s = 0.f;
    for(int c=0;c<H;c++) s += w[c]*a[c];
    wvec[t] = s;
}

__global__ void k_count(const int* __restrict__ dst, int* __restrict__ cnt, int E){
    int e = blockIdx.x*256 + threadIdx.x;
    if(e < E) atomicAdd(&cnt[dst[e]], 1);
}

// exclusive prefix sum over n counts -> rowptr[0..n] (single block, shuffle scan)
__global__ __launch_bounds__(1024) void k_scan(const int* __restrict__ cnt, int* __restrict__ rowptr, int n){
    __shared__ int ws[16];
    __shared__ int carrysh;
    int t = threadIdx.x, lane = t & 63, wv = t >> 6;
    if(t==0){ carrysh = 0; rowptr[0] = 0; }
    __syncthreads();
    for(int base=0; base<n; base+=1024){
        int i = base + t;
        int v = (i<n) ? cnt[i] : 0;
        int s = v;
        #pragma unroll
        for(int off=1; off<64; off<<=1){ int u = __shfl_up(s, off, 64); if(lane>=off) s += u; }
        if(lane==63) ws[wv] = s;
        __syncthreads();
        if(t < 16){
            int u = ws[t];
            #pragma unroll
            for(int off=1; off<16; off<<=1){ int u2 = __shfl_up(u, off, 16); if(t>=off) u += u2; }
            ws[t] = u;
        }
        __syncthreads();
        int carry = carrysh;
        int wbase = wv ? ws[wv-1] : 0;
        if(i<n) rowptr[i+1] = carry + wbase + s;
        int total = ws[15];
        __syncthreads();
        if(t==0) carrysh = carry + total;
        __syncthreads();
    }
}

__global__ void k_scatter(const int* __restrict__ dst, const int* __restrict__ rowptr,
                          int* __restrict__ cnt2, int* __restrict__ eid, int E){
    int e = blockIdx.x*256 + threadIdx.x;
    if(e >= E) return;
    int d = dst[e];
    int p = rowptr[d] + atomicAdd(&cnt2[d], 1);
    eid[p] = e;
}

// deterministic order: sort each node's edge list by original edge id
__global__ void k_sort(const int* __restrict__ rowptr, int* __restrict__ eid, int n){
    int v = blockIdx.x*256 + threadIdx.x;
    if(v >= n) return;
    int b = rowptr[v], e = rowptr[v+1];
    for(int i=b+1; i<e; i++){
        int key = eid[i]; int j = i-1;
        while(j>=b && eid[j] > key){ eid[j+1] = eid[j]; j--; }
        eid[j+1] = key;
    }
}

// per CSR slot: csr_src and a_e for all 6 layers
__global__ __launch_bounds__(256) void k_ae(const int* __restrict__ eid, const int* __restrict__ src,
                     const int* __restrict__ eattr, const float* __restrict__ emb,
                     const float* __restrict__ wvec, int* __restrict__ csrsrc,
                     float* __restrict__ ae, int E){
    __shared__ float wv[6*128];
    for(int i=threadIdx.x; i<6*128; i+=256) wv[i] = wvec[i];
    __syncthreads();
    int p = blockIdx.x*256 + threadIdx.x;
    if(p >= E) return;
    int e = eid[p];
    csrsrc[p] = src[e];
    const float4* er = (const float4*)(emb + (size_t)eattr[e]*128);
    float acc[6] = {0,0,0,0,0,0};
    for(int k=0;k<32;k++){
        float4 v = er[k];
        #pragma unroll
        for(int l=0;l<6;l++){
            const float* w = wv + l*128 + k*4;
            acc[l] += v.x*w[0] + v.y*w[1] + v.z*w[2] + v.w*w[3];
        }
    }
    #pragma unroll
    for(int l=0;l<6;l++) ae[(size_t)l*E + p] = acc[l];
}

// a_e for the self loop: mean of incoming a_e (deterministic sequential sum)
__global__ void k_aeloop(const int* __restrict__ rowptr, const float* __restrict__ ae,
                         float* __restrict__ ael, int n, int E){
    int v = blockIdx.x*256 + threadIdx.x;
    if(v >= n) return;
    int b = rowptr[v], e = rowptr[v+1];
    float dg = fmaxf((float)(e-b), 1.0f);
    #pragma unroll
    for(int l=0;l<6;l++){
        float s = 0.f;
        for(int p=b;p<e;p++) s += ae[(size_t)l*E + p];
        ael[(size_t)l*n + v] = s / dg;
    }
}

// ---------------- layer-0 h: gather emb -> x tile -> h = x@W, a_s, a_d ----------------

__global__ __launch_bounds__(512) void k_hx(const int* __restrict__ xidx, const float* __restrict__ emb,
        const float* __restrict__ W, const float* __restrict__ atts, const float* __restrict__ attd,
        float* __restrict__ h, float* __restrict__ as_, float* __restrict__ ad_, int n){
    __shared__ float xs[64][129];
    __shared__ float hs[64][65];
    __shared__ float redA[8][64], redB[8][64];
    int base = blockIdx.x*64;
    int t = threadIdx.x;
    {   // stage x tile: 64 rows x 128, 16 floats/thread
        int r = t>>3, c0 = (t&7)*16;
        if(base + r < n){
            const float4* srcp = (const float4*)(emb + (size_t)xidx[base+r]*128 + c0);
            #pragma unroll
            for(int q=0;q<4;q++){
                float4 v = srcp[q];
                xs[r][c0+q*4+0]=v.x; xs[r][c0+q*4+1]=v.y; xs[r][c0+q*4+2]=v.z; xs[r][c0+q*4+3]=v.w;
            }
        } else {
            #pragma unroll
            for(int q=0;q<16;q++) xs[r][c0+q] = 0.f;
        }
    }
    __syncthreads();
    int lane = t & 63;
    int wid = __builtin_amdgcn_readfirstlane(t >> 6);
    int cb = wid*8;
    float acc[8] = {0,0,0,0,0,0,0,0};
    for(int k=0;k<128;k++){
        float xv = xs[lane][k];
        #pragma unroll
        for(int cc=0;cc<8;cc++) acc[cc] = fmaf(xv, W[k*64 + cb + cc], acc[cc]);
    }
    float pa=0.f, pd=0.f;
    #pragma unroll
    for(int cc=0;cc<8;cc++){
        hs[lane][cb+cc] = acc[cc];
        pa += acc[cc]*atts[cb+cc];
        pd += acc[cc]*attd[cb+cc];
    }
    redA[wid][lane]=pa; redB[wid][lane]=pd;
    __syncthreads();
    {   // coalesced h store
        int r = t>>3, c0 = (t&7)*8;
        if(base + r < n){
            float* dst = h + (size_t)(base+r)*64 + c0;
            #pragma unroll
            for(int q=0;q<8;q++) dst[q] = hs[r][c0+q];
        }
    }
    if(t < 64 && base + t < n){
        float sa=0.f, sd=0.f;
        #pragma unroll
        for(int w=0;w<8;w++){ sa += redA[w][t]; sd += redB[w][t]; }
        as_[base+t] = sa; ad_[base+t] = sd;
    }
}

// ---------------- fused layer: GAT + MLP3 + JKN + next-layer h/a_s/a_d ----------------

__global__ __launch_bounds__(512) void k_layer(
    const float* __restrict__ h, const float* __restrict__ as_, const float* __restrict__ ad_,
    const float* __restrict__ ae, const float* __restrict__ ael,
    const int* __restrict__ rowptr, const int* __restrict__ csrsrc,
    const float* __restrict__ bias,
    const float* __restrict__ W1, const float* __restrict__ b1,
    const float* __restrict__ W2, const float* __restrict__ b2,
    const float* __restrict__ W3, const float* __restrict__ b3,
    float* __restrict__ bestF, float* __restrict__ bestMs, int layer,
    const float* __restrict__ Wn, const float* __restrict__ atts, const float* __restrict__ attd,
    float* __restrict__ hn, float* __restrict__ asn, float* __restrict__ adn_,
    int n, int last)
{
    __shared__ float o_s[64][65];   // gat out, reused as t2
    __shared__ float t1[64][65];    // mlp hidden, reused as h_next staging
    __shared__ float xs[64][129];   // mlp output (x' tile)
    __shared__ float redA[8][64], redB[8][64];
    __shared__ unsigned char updf[64];
    int base = blockIdx.x*64;
    int t = threadIdx.x, lane = t & 63;
    int wid = __builtin_amdgcn_readfirstlane(t >> 6);

    // ---- Phase A: GAT, wave handles 8 nodes (online softmax over incoming + self loop)
    {
        float bi = bias[lane];
        for(int nn=0; nn<8; nn++){
            int nl = wid*8 + nn, node = base + nl;
            if(node >= n) break;
            int b = rowptr[node], e = rowptr[node+1];
            float adv = ad_[node];
            float m = lrelu(as_[node] + adv + ael[node]);
            float d = 1.0f;                                   // self loop
            float acc = h[(size_t)node*64 + lane];
            for(int j0=b; j0<e; j0+=64){
                int nj = min(64, e-j0);
                int sj = 0; float lg = -1e30f;
                if(lane < nj){
                    sj = csrsrc[j0+lane];
                    lg = lrelu(as_[sj] + adv + ae[j0+lane]);
                }
                float cm = lg;
                #pragma unroll
                for(int off=32; off; off>>=1) cm = fmaxf(cm, __shfl_xor(cm,off,64));
                float nm = fmaxf(m, cm);
                float w = (lane<nj) ? expf(lg-nm) : 0.0f;
                float ws = w;
                #pragma unroll
                for(int off=32; off; off>>=1) ws += __shfl_xor(ws,off,64);
                float scale = expf(m-nm);
                d = d*scale + ws;
                acc *= scale;
                #pragma unroll 4
                for(int j=0;j<nj;j++){
                    float wj = bcastf(w, j);
                    int s = __builtin_amdgcn_readlane(sj, j);
                    acc = fmaf(wj, h[(size_t)s*64 + lane], acc);
                }
                m = nm;
            }
            o_s[nl][lane] = acc/d + bi;
        }
    }
    __syncthreads();

    // ---- Phase B: t1 = relu(o @ W1 + b1), 8 cols/lane (uniform W -> s_load)
    {
        int cb = wid*8;
        float acc[8];
        #pragma unroll
        for(int cc=0;cc<8;cc++) acc[cc] = b1[cb+cc];
        for(int k=0;k<64;k++){
            float ov = o_s[lane][k];
            #pragma unroll
            for(int cc=0;cc<8;cc++) acc[cc] = fmaf(ov, W1[k*64 + cb + cc], acc[cc]);
        }
        #pragma unroll
        for(int cc=0;cc<8;cc++) t1[lane][cb+cc] = fmaxf(acc[cc], 0.f);
    }
    __syncthreads();

    // ---- Phase C: t2 = relu(t1 @ W2 + b2) -> o_s (reuse)
    {
        int cb = wid*8;
        float acc[8];
        #pragma unroll
        for(int cc=0;cc<8;cc++) acc[cc] = b2[cb+cc];
        for(int k=0;k<64;k++){
            float tv = t1[lane][k];
            #pragma unroll
            for(int cc=0;cc<8;cc++) acc[cc] = fmaf(tv, W2[k*64 + cb + cc], acc[cc]);
        }
        __syncthreads();
        #pragma unroll
        for(int cc=0;cc<8;cc++) o_s[lane][cb+cc] = fmaxf(acc[cc], 0.f);
    }
    __syncthreads();

    // ---- Phase D: x' = t2 @ W3 + b3 (128 out, 16/lane) -> xs; ms partial
    {
        int cb = wid*16;
        float acc[16];
        #pragma unroll
        for(int cc=0;cc<16;cc++) acc[cc] = b3[cb+cc];
        for(int k=0;k<64;k++){
            float tv = o_s[lane][k];
            #pragma unroll
            for(int cc=0;cc<16;cc++) acc[cc] = fmaf(tv, W3[k*128 + cb + cc], acc[cc]);
        }
        float ms = 0.f;
        #pragma unroll
        for(int cc=0;cc<16;cc++){ xs[lane][cb+cc] = acc[cc]; ms += acc[cc]*acc[cc]; }
        redA[wid][lane] = ms;
    }
    __syncthreads();

    // ---- JKN decision
    if(t < 64){
        int node = base + t; bool u = false;
        if(node < n){
            float ms = 0.f;
            #pragma unroll
            for(int w=0;w<8;w++) ms += redA[w][t];
            u = (layer==0) || (ms > bestMs[node]);
            if(u) bestMs[node] = ms;
        }
        updf[t] = u ? 1 : 0;
    }
    __syncthreads();
    {   // conditional bestF row copy, coalesced-ish
        int r = t>>3, c0 = (t&7)*16;
        if(updf[r] && base + r < n){
            float* dst = bestF + (size_t)(base+r)*128 + c0;
            #pragma unroll
            for(int q=0;q<16;q++) dst[q] = xs[r][c0+q];
        }
    }
    if(last) return;

    // ---- Phase F: h_next = x' @ Wn (8/lane) + a_s/a_d for next layer
    {
        int cb = wid*8;
        float acc[8] = {0,0,0,0,0,0,0,0};
        for(int k=0;k<128;k++){
            float xv = xs[lane][k];
            #pragma unroll
            for(int cc=0;cc<8;cc++) acc[cc] = fmaf(xv, Wn[k*64 + cb + cc], acc[cc]);
        }
        float pa=0.f, pd=0.f;
        #pragma unroll
        for(int cc=0;cc<8;cc++){
            t1[lane][cb+cc] = acc[cc];
            pa += acc[cc]*atts[cb+cc];
            pd += acc[cc]*attd[cb+cc];
        }
        redA[wid][lane]=pa; redB[wid][lane]=pd;
    }
    __syncthreads();
    {
        int r = t>>3, c0 = (t&7)*8;
        if(base + r < n){
            float* dst = hn + (size_t)(base+r)*64 + c0;
            #pragma unroll
            for(int q=0;q<8;q++) dst[q] = t1[r][c0+q];
        }
    }
    if(t < 64 && base + t < n){
        float sa=0.f, sd=0.f;
        #pragma unroll
        for(int w=0;w<8;w++){ sa += redA[w][t]; sd += redB[w][t]; }
        asn[base+t] = sa; adn_[base+t] = sd;
    }
}

// ---------------- pooling ----------------

__global__ __launch_bounds__(512) void k_pool1(const float* __restrict__ F,
        const float* __restrict__ A, const float* __restrict__ g1b1,
        const float* __restrict__ w2, const float* __restrict__ g1b2,
        const float* __restrict__ B, const float* __restrict__ g2b1,
        const float* __restrict__ C, const float* __restrict__ g2b2,
        float* __restrict__ h1, float* __restrict__ h2, int n){
    __shared__ float fs[64][129];
    __shared__ float ts[64][65];
    __shared__ float red[4][64];
    int base = blockIdx.x*64, t = threadIdx.x, lane = t & 63;
    int wid = __builtin_amdgcn_readfirstlane(t >> 6);
    {
        int r = t>>3, c0 = (t&7)*16;
        if(base + r < n){
            const float4* srcp = (const float4*)(F + (size_t)(base+r)*128 + c0);
            #pragma unroll
            for(int q=0;q<4;q++){
                float4 v = srcp[q];
                fs[r][c0+q*4+0]=v.x; fs[r][c0+q*4+1]=v.y; fs[r][c0+q*4+2]=v.z; fs[r][c0+q*4+3]=v.w;
            }
        } else {
            #pragma unroll
            for(int q=0;q<16;q++) fs[r][c0+q] = 0.f;
        }
    }
    __syncthreads();
    if(wid < 4){                      // p1 = relu(F@A+b); partial h1 = dot(p1, w2)
        int cb = wid*16;
        float acc[16];
        #pragma unroll
        for(int cc=0;cc<16;cc++) acc[cc] = g1b1[cb+cc];
        for(int k=0;k<128;k++){
            float fv = fs[lane][k];
            #pragma unroll
            for(int cc=0;cc<16;cc++) acc[cc] = fmaf(fv, A[k*64 + cb + cc], acc[cc]);
        }
        float pp = 0.f;
        #pragma unroll
        for(int cc=0;cc<16;cc++) pp += fmaxf(acc[cc],0.f)*w2[cb+cc];
        red[wid][lane] = pp;
    } else {                          // p2 = relu(F@B+b) -> ts
        int cb = (wid-4)*16;
        float acc[16];
        #pragma unroll
        for(int cc=0;cc<16;cc++) acc[cc] = g2b1[cb+cc];
        for(int k=0;k<128;k++){
            float fv = fs[lane][k];
            #pragma unroll
            for(int cc=0;cc<16;cc++) acc[cc] = fmaf(fv, B[k*64 + cb + cc], acc[cc]);
        }
        #pragma unroll
        for(int cc=0;cc<16;cc++) ts[lane][cb+cc] = fmaxf(acc[cc],0.f);
    }
    __syncthreads();
    if(t < 64 && base + t < n)
        h1[base+t] = red[0][t]+red[1][t]+red[2][t]+red[3][t] + g1b2[0];
    {   // h2 = ts @ C + b (128 out, 16/lane) -> fs reuse
        int cb = wid*16;
        float acc[16];
        #pragma unroll
        for(int cc=0;cc<16;cc++) acc[cc] = g2b2[cb+cc];
        for(int k=0;k<64;k++){
            float tv = ts[lane][k];
            #pragma unroll
            for(int cc=0;cc<16;cc++) acc[cc] = fmaf(tv, C[k*128 + cb + cc], acc[cc]);
        }
        __syncthreads();
        #pragma unroll
        for(int cc=0;cc<16;cc++) fs[lane][cb+cc] = acc[cc];
    }
    __syncthreads();
    {
        int r = t>>3, c0 = (t&7)*16;
        if(base + r < n){
            float* dst = h2 + (size_t)(base+r)*128 + c0;
            #pragma unroll
            for(int q=0;q<16;q++) dst[q] = fs[r][c0+q];
        }
    }
}

__global__ __launch_bounds__(128) void k_pool2(const float* __restrict__ h1, const float* __restrict__ h2,
                      float* __restrict__ wbuf, float* __restrict__ hg, int n, int G){
    __shared__ float sh[128];
    int g = blockIdx.x, tid = threadIdx.x;
    int start = (g*n + G-1)/G, end = ((g+1)*n + G-1)/G;
    float lm = -1e30f;
    for(int i=start+tid; i<end; i+=128) lm = fmaxf(lm, h1[i]);
    sh[tid]=lm; __syncthreads();
    for(int off=64; off; off>>=1){ if(tid<off) sh[tid]=fmaxf(sh[tid],sh[tid+off]); __syncthreads(); }
    float m = sh[0]; __syncthreads();
    float lsum = 0.f;
    for(int i=start+tid; i<end; i+=128){ float w = expf(h1[i]-m); wbuf[i]=w; lsum+=w; }
    sh[tid]=lsum; __syncthreads();
    for(int off=64; off; off>>=1){ if(tid<off) sh[tid]+=sh[tid+off]; __syncthreads(); }
    float denom = sh[0];
    float a0=0.f,a1=0.f,a2=0.f,a3=0.f;
    int i = start;
    for(; i+3<end; i+=4){
        a0 = fmaf(wbuf[i+0], h2[(size_t)(i+0)*128 + tid], a0);
        a1 = fmaf(wbuf[i+1], h2[(size_t)(i+1)*128 + tid], a1);
        a2 = fmaf(wbuf[i+2], h2[(size_t)(i+2)*128 + tid], a2);
        a3 = fmaf(wbuf[i+3], h2[(size_t)(i+3)*128 + tid], a3);
    }
    for(; i<end; i++) a0 = fmaf(wbuf[i], h2[(size_t)i*128 + tid], a0);
    float acc = (a0+a1)+(a2+a3);
    hg[g*128 + tid] = acc/denom/(float)(end-start);
}

__global__ __launch_bounds__(256) void k_final(const float* __restrict__ hg,
                      const float* __restrict__ pW1, const float* __restrict__ pb1,
                      const float* __restrict__ pW2, const float* __restrict__ pb2,
                      const float* __restrict__ pW3, const float* __restrict__ pb3,
                      float* __restrict__ out, int G){
    int lane = threadIdx.x & 63, wid = threadIdx.x >> 6;
    for(int g = wid; g < G; g += 4){
        const float* r = hg + g*128;
        float t1 = pb1[lane];
        for(int k=0;k<128;k++) t1 += r[k]*pW1[k*64+lane];
        t1 = fmaxf(t1,0.f);
        float t2 = pb2[lane];
        for(int k=0;k<64;k++) t2 += __shfl(t1,k,64)*pW2[k*64+lane];
        t2 = fmaxf(t2,0.f);
        float s = t2*pW3[lane];
        #pragma unroll
        for(int off=32; off; off>>=1) s += __shfl_xor(s,off,64);
        if(lane==0) out[g] = s + pb3[0];
    }
}

extern "C" void kernel_launch(void* const* d_in, const int* in_sizes, int n_in,
                              void* d_out, int out_size, void* d_ws, size_t ws_size,
                              hipStream_t stream){
    const int*   x_idx   = (const int*)  d_in[0];
    const int*   eindex  = (const int*)  d_in[1];
    const int*   eattr   = (const int*)  d_in[2];
    const float* emb     = (const float*)d_in[4];
    const float* conv_W  = (const float*)d_in[5];
    const float* conv_We = (const float*)d_in[6];
    const float* att_src = (const float*)d_in[7];
    const float* att_dst = (const float*)d_in[8];
    const float* att_edg = (const float*)d_in[9];
    const float* conv_b  = (const float*)d_in[10];
    const float* mW1 = (const float*)d_in[11]; const float* mb1 = (const float*)d_in[12];
    const float* mW2 = (const float*)d_in[13]; const float* mb2 = (const float*)d_in[14];
    const float* mW3 = (const float*)d_in[15]; const float* mb3 = (const float*)d_in[16];
    const float* g1W1= (const float*)d_in[17]; const float* g1b1= (const float*)d_in[18];
    const float* g1W2= (const float*)d_in[19]; const float* g1b2= (const float*)d_in[20];
    const float* g2W1= (const float*)d_in[21]; const float* g2b1= (const float*)d_in[22];
    const float* g2W2= (const float*)d_in[23]; const float* g2b2= (const float*)d_in[24];
    const float* pW1 = (const float*)d_in[25]; const float* pb1 = (const float*)d_in[26];
    const float* pW2 = (const float*)d_in[27]; const float* pb2 = (const float*)d_in[28];
    const float* pW3 = (const float*)d_in[29]; const float* pb3 = (const float*)d_in[30];

    const int N = in_sizes[0];
    const int E = in_sizes[2];
    const int G = out_size;
    const int* src = eindex;
    const int* dst = eindex + E;
    const int NT = (N + 63) / 64;

    char* p = (char*)d_ws;
    auto alloc = [&](size_t bytes)->void*{ void* r = (void*)p; p += (bytes + 255) & ~(size_t)255; return r; };
    float* hA     = (float*)alloc((size_t)N*64*4);
    float* hB     = (float*)alloc((size_t)N*64*4);
    float* bestF  = (float*)alloc((size_t)N*128*4);
    float* h2buf  = (float*)alloc((size_t)N*128*4);
    float* bestMs = (float*)alloc((size_t)N*4);
    float* asA    = (float*)alloc((size_t)N*4);
    float* adA    = (float*)alloc((size_t)N*4);
    float* asB    = (float*)alloc((size_t)N*4);
    float* adB    = (float*)alloc((size_t)N*4);
    float* ae     = (float*)alloc((size_t)6*E*4);
    float* ael    = (float*)alloc((size_t)6*N*4);
    float* wvec   = (float*)alloc(6*128*4);
    float* h1     = (float*)alloc((size_t)N*4);
    float* hg     = (float*)alloc((size_t)G*128*4);
    int*   cnt    = (int*)  alloc((size_t)N*4);
    int*   cnt2   = (int*)  alloc((size_t)N*4);
    int*   rowptr = (int*)  alloc((size_t)(N+1)*4);
    int*   eid    = (int*)  alloc((size_t)E*4);
    int*   csrsrc = (int*)  alloc((size_t)E*4);

    hipMemsetAsync(cnt,  0, (size_t)N*4, stream);
    hipMemsetAsync(cnt2, 0, (size_t)N*4, stream);

    k_wvec<<<(6*128+255)/256, 256, 0, stream>>>(conv_We, att_edg, wvec, 6, 128, 64);
    k_count<<<(E+255)/256, 256, 0, stream>>>(dst, cnt, E);
    k_scan<<<1, 1024, 0, stream>>>(cnt, rowptr, N);
    k_scatter<<<(E+255)/256, 256, 0, stream>>>(dst, rowptr, cnt2, eid, E);
    k_sort<<<(N+255)/256, 256, 0, stream>>>(rowptr, eid, N);
    k_ae<<<(E+255)/256, 256, 0, stream>>>(eid, src, eattr, emb, wvec, csrsrc, ae, E);
    k_aeloop<<<(N+255)/256, 256, 0, stream>>>(rowptr, ae, ael, N, E);

    k_hx<<<NT, 512, 0, stream>>>(x_idx, emb, conv_W, att_src, att_dst, hA, asA, adA, N);

    const float* hin = hA;  float* hout = hB;
    const float* asin_ = asA; const float* adin = adA;
    float* asout = asB; float* adout = adB;
    for(int l=0; l<6; l++){
        int last = (l==5) ? 1 : 0;
        const float* Wn   = last ? conv_W  : conv_W  + (size_t)(l+1)*8192;
        const float* atsn = last ? att_src : att_src + (l+1)*64;
        const float* atdn = last ? att_dst : att_dst + (l+1)*64;
        k_layer<<<NT, 512, 0, stream>>>(hin, asin_, adin,
            ae + (size_t)l*E, ael + (size_t)l*N, rowptr, csrsrc, conv_b + l*64,
            mW1 + (size_t)l*4096, mb1 + l*64, mW2 + (size_t)l*4096, mb2 + l*64,
            mW3 + (size_t)l*8192, mb3 + l*128,
            bestF, bestMs, l,
            Wn, atsn, atdn,
            hout, asout, adout, N, last);
        // swap ping-pong
        const float* th = hin; hin = hout; hout = (float*)th;
        const float* ts_ = asin_; asin_ = asout; asout = (float*)ts_;
        const float* td = adin; adin = adout; adout = (float*)td;
    }

    k_pool1<<<NT, 512, 0, stream>>>(bestF, g1W1, g1b1, g1W2, g1b2, g2W1, g2b1, g2W2, g2b2, h1, h2buf, N);
    k_pool2<<<G, 128, 0, stream>>>(h1, h2buf, asA, hg, N, G);
    k_final<<<1, 256, 0, stream>>>(hg, pW1, pb1, pW2, pb2, pW3, pb3, (float*)d_out, G);
}

// Round 3
// 540.137 us; speedup vs baseline: 2.1484x; 1.3438x over previous
//
#include <hip/hip_runtime.h>
#include <math.h>

__device__ __forceinline__ float lrelu(float x){ return x > 0.0f ? x : 0.2f*x; }
__device__ __forceinline__ float bcastf(float v, int l){
    return __int_as_float(__builtin_amdgcn_readlane(__float_as_int(v), l));
}

// ---------------- precompute ----------------

__global__ void k_count(const int* __restrict__ dst, int* __restrict__ cnt, int E){
    int e = blockIdx.x*256 + threadIdx.x;
    if(e < E) atomicAdd(&cnt[dst[e]], 1);
}

// exclusive prefix sum over n counts -> rowptr[0..n] (single block, shuffle scan)
__global__ __launch_bounds__(1024) void k_scan(const int* __restrict__ cnt, int* __restrict__ rowptr, int n){
    __shared__ int ws[16];
    __shared__ int carrysh;
    int t = threadIdx.x, lane = t & 63, wv = t >> 6;
    if(t==0){ carrysh = 0; rowptr[0] = 0; }
    __syncthreads();
    for(int base=0; base<n; base+=1024){
        int i = base + t;
        int v = (i<n) ? cnt[i] : 0;
        int s = v;
        #pragma unroll
        for(int off=1; off<64; off<<=1){ int u = __shfl_up(s, off, 64); if(lane>=off) s += u; }
        if(lane==63) ws[wv] = s;
        __syncthreads();
        if(t < 16){
            int u = ws[t];
            #pragma unroll
            for(int off=1; off<16; off<<=1){ int u2 = __shfl_up(u, off, 16); if(t>=off) u += u2; }
            ws[t] = u;
        }
        __syncthreads();
        int carry = carrysh;
        int wbase = wv ? ws[wv-1] : 0;
        if(i<n) rowptr[i+1] = carry + wbase + s;
        int total = ws[15];
        __syncthreads();
        if(t==0) carrysh = carry + total;
        __syncthreads();
    }
}

__global__ void k_scatter(const int* __restrict__ dst, const int* __restrict__ rowptr,
                          int* __restrict__ cnt2, int* __restrict__ eid, int E){
    int e = blockIdx.x*256 + threadIdx.x;
    if(e >= E) return;
    int d = dst[e];
    int p = rowptr[d] + atomicAdd(&cnt2[d], 1);
    eid[p] = e;
}

// deterministic CSR order: in-register bitonic sort of each node's edge ids (wave per node)
__global__ __launch_bounds__(256) void k_sortb(const int* __restrict__ rowptr, int* __restrict__ eid, int n){
    int node = blockIdx.x*4 + (threadIdx.x>>6);
    if(node >= n) return;
    int lane = threadIdx.x & 63;
    int b = rowptr[node], e = rowptr[node+1];
    int nj = e - b;
    if(nj <= 1) return;
    if(nj <= 64){
        int v = (lane < nj) ? eid[b+lane] : 0x7fffffff;
        for(int k=2; k<=64; k<<=1){
            for(int j=k>>1; j>0; j>>=1){
                int vv = __shfl_xor(v, j, 64);
                bool up = ((lane & k) == 0);
                bool lower = ((lane & j) == 0);
                int mn = min(v,vv), mx = max(v,vv);
                v = (lower == up) ? mn : mx;
            }
        }
        if(lane < nj) eid[b+lane] = v;
    } else if(lane == 0){          // vanishingly rare (deg>64): fallback insertion sort
        for(int i=b+1; i<e; i++){
            int key = eid[i]; int j = i-1;
            while(j>=b && eid[j] > key){ eid[j+1] = eid[j]; j--; }
            eid[j+1] = key;
        }
    }
}

// per CSR slot: csr_src and a_e for all 6 layers (wvec computed in-block)
__global__ __launch_bounds__(256) void k_ae(const int* __restrict__ eid, const int* __restrict__ src,
                     const int* __restrict__ eattr, const float* __restrict__ emb,
                     const float* __restrict__ We, const float* __restrict__ atte,
                     int* __restrict__ csrsrc, float* __restrict__ ae, int E){
    __shared__ float wv[6*128];
    for(int i=threadIdx.x; i<768; i+=256){
        int l = i>>7, k = i&127;
        const float* w = We + ((size_t)l*128 + k)*64;
        const float* a = atte + l*64;
        float s = 0.f;
        #pragma unroll 8
        for(int c=0;c<64;c++) s += w[c]*a[c];
        wv[i] = s;
    }
    __syncthreads();
    int p = blockIdx.x*256 + threadIdx.x;
    if(p >= E) return;
    int e = eid[p];
    csrsrc[p] = src[e];
    const float4* er = (const float4*)(emb + (size_t)eattr[e]*128);
    float acc[6] = {0,0,0,0,0,0};
    for(int k=0;k<32;k++){
        float4 v = er[k];
        #pragma unroll
        for(int l=0;l<6;l++){
            const float* w = wv + l*128 + k*4;
            acc[l] += v.x*w[0] + v.y*w[1] + v.z*w[2] + v.w*w[3];
        }
    }
    #pragma unroll
    for(int l=0;l<6;l++) ae[(size_t)l*E + p] = acc[l];
}

// ---------------- layer-0 h: gather emb -> x tile -> h = x@W, a_s, a_d ----------------

__global__ __launch_bounds__(512) void k_hx(const int* __restrict__ xidx, const float* __restrict__ emb,
        const float* __restrict__ W, const float* __restrict__ atts, const float* __restrict__ attd,
        float* __restrict__ h, float* __restrict__ as_, float* __restrict__ ad_, int n){
    __shared__ float xs[64][129];
    __shared__ float hs[64][65];
    __shared__ float redA[8][64], redB[8][64];
    int base = blockIdx.x*64;
    int t = threadIdx.x;
    {
        int r = t>>3, c0 = (t&7)*16;
        if(base + r < n){
            const float4* srcp = (const float4*)(emb + (size_t)xidx[base+r]*128 + c0);
            #pragma unroll
            for(int q=0;q<4;q++){
                float4 v = srcp[q];
                xs[r][c0+q*4+0]=v.x; xs[r][c0+q*4+1]=v.y; xs[r][c0+q*4+2]=v.z; xs[r][c0+q*4+3]=v.w;
            }
        } else {
            #pragma unroll
            for(int q=0;q<16;q++) xs[r][c0+q] = 0.f;
        }
    }
    __syncthreads();
    int lane = t & 63;
    int wid = __builtin_amdgcn_readfirstlane(t >> 6);
    int cb = wid*8;
    float acc[8] = {0,0,0,0,0,0,0,0};
    for(int k=0;k<128;k++){
        float xv = xs[lane][k];
        #pragma unroll
        for(int cc=0;cc<8;cc++) acc[cc] = fmaf(xv, W[k*64 + cb + cc], acc[cc]);
    }
    float pa=0.f, pd=0.f;
    #pragma unroll
    for(int cc=0;cc<8;cc++){
        hs[lane][cb+cc] = acc[cc];
        pa += acc[cc]*atts[cb+cc];
        pd += acc[cc]*attd[cb+cc];
    }
    redA[wid][lane]=pa; redB[wid][lane]=pd;
    __syncthreads();
    {
        int r = t>>3, c0 = (t&7)*8;
        if(base + r < n){
            float* dst = h + (size_t)(base+r)*64 + c0;
            #pragma unroll
            for(int q=0;q<8;q++) dst[q] = hs[r][c0+q];
        }
    }
    if(t < 64 && base + t < n){
        float sa=0.f, sd=0.f;
        #pragma unroll
        for(int w=0;w<8;w++){ sa += redA[w][t]; sd += redB[w][t]; }
        as_[base+t] = sa; ad_[base+t] = sd;
    }
}

// ---------------- GAT aggregation: wave per node ----------------

__global__ __launch_bounds__(256) void k_gat(const float* __restrict__ h,
        const float* __restrict__ as_, const float* __restrict__ ad_,
        const float* __restrict__ ae, const int* __restrict__ rowptr,
        const int* __restrict__ csrsrc, const float* __restrict__ bias,
        float* __restrict__ o, int n){
    int node = blockIdx.x*4 + (threadIdx.x>>6);
    if(node >= n) return;
    int lane = threadIdx.x & 63;
    int b = rowptr[node], e = rowptr[node+1];
    float adv = ad_[node];
    float m = -1e30f, d = 0.f, sumae = 0.f;
    float a0=0.f, a1=0.f, a2=0.f, a3=0.f;
    for(int j0=b; j0<e; j0+=64){
        int nj = min(64, e-j0);
        int sj = 0; float aev = 0.f, lg = -1e30f;
        if(lane < nj){
            sj  = csrsrc[j0+lane];
            aev = ae[j0+lane];
            lg  = lrelu(as_[sj] + adv + aev);
        }
        float cm = lg, sa = aev;
        #pragma unroll
        for(int off=32; off; off>>=1){ cm = fmaxf(cm, __shfl_xor(cm,off,64)); sa += __shfl_xor(sa,off,64); }
        sumae += sa;
        float nm = fmaxf(m, cm);
        float w = (lane<nj) ? expf(lg-nm) : 0.f;
        float ws = w;
        #pragma unroll
        for(int off=32; off; off>>=1) ws += __shfl_xor(ws,off,64);
        float scale = (m > -1e29f) ? expf(m-nm) : 0.f;
        d = d*scale + ws;
        a0*=scale; a1*=scale; a2*=scale; a3*=scale;
        int j = 0;
        for(; j+3<nj; j+=4){
            a0 = fmaf(bcastf(w,j+0), h[(size_t)__builtin_amdgcn_readlane(sj,j+0)*64 + lane], a0);
            a1 = fmaf(bcastf(w,j+1), h[(size_t)__builtin_amdgcn_readlane(sj,j+1)*64 + lane], a1);
            a2 = fmaf(bcastf(w,j+2), h[(size_t)__builtin_amdgcn_readlane(sj,j+2)*64 + lane], a2);
            a3 = fmaf(bcastf(w,j+3), h[(size_t)__builtin_amdgcn_readlane(sj,j+3)*64 + lane], a3);
        }
        for(; j<nj; j++)
            a0 = fmaf(bcastf(w,j), h[(size_t)__builtin_amdgcn_readlane(sj,j)*64 + lane], a0);
        m = nm;
    }
    int deg = e - b;
    float ael = sumae / fmaxf((float)deg, 1.f);
    float ls = lrelu(as_[node] + adv + ael);
    float nm = fmaxf(m, ls);
    float scale = (m > -1e29f) ? expf(m-nm) : 0.f;
    float wl = expf(ls-nm);
    d = d*scale + wl;
    float acc = (a0+a1)+(a2+a3);
    acc = acc*scale + wl*h[(size_t)node*64 + lane];
    o[(size_t)node*64 + lane] = acc/d + bias[lane];
}

// ---------------- dense: MLP3 + JKN + next-layer h/a_s/a_d ----------------

__global__ __launch_bounds__(512) void k_dense(
    const float* __restrict__ o,
    const float* __restrict__ W1, const float* __restrict__ b1,
    const float* __restrict__ W2, const float* __restrict__ b2,
    const float* __restrict__ W3, const float* __restrict__ b3,
    float* __restrict__ bestF, float* __restrict__ bestMs, int layer,
    const float* __restrict__ Wn, const float* __restrict__ atts, const float* __restrict__ attd,
    float* __restrict__ hn, float* __restrict__ asn, float* __restrict__ adn_,
    int n, int last)
{
    __shared__ float o_s[64][65];   // o tile, reused as t2
    __shared__ float t1[64][65];    // mlp hidden, reused as h_next staging
    __shared__ float xs[64][129];   // mlp output (x' tile)
    __shared__ float redA[8][64], redB[8][64];
    __shared__ unsigned char updf[64];
    int base = blockIdx.x*64;
    int t = threadIdx.x, lane = t & 63;
    int wid = __builtin_amdgcn_readfirstlane(t >> 6);

    {   // stage o tile (coalesced)
        int r = t>>3, c0 = (t&7)*8;
        if(base + r < n){
            const float4* srcp = (const float4*)(o + (size_t)(base+r)*64 + c0);
            float4 v0 = srcp[0], v1 = srcp[1];
            o_s[r][c0+0]=v0.x; o_s[r][c0+1]=v0.y; o_s[r][c0+2]=v0.z; o_s[r][c0+3]=v0.w;
            o_s[r][c0+4]=v1.x; o_s[r][c0+5]=v1.y; o_s[r][c0+6]=v1.z; o_s[r][c0+7]=v1.w;
        } else {
            #pragma unroll
            for(int q=0;q<8;q++) o_s[r][c0+q] = 0.f;
        }
    }
    __syncthreads();

    // ---- t1 = relu(o @ W1 + b1), 8 cols/lane (uniform W -> s_load)
    {
        int cb = wid*8;
        float acc[8];
        #pragma unroll
        for(int cc=0;cc<8;cc++) acc[cc] = b1[cb+cc];
        for(int k=0;k<64;k++){
            float ov = o_s[lane][k];
            #pragma unroll
            for(int cc=0;cc<8;cc++) acc[cc] = fmaf(ov, W1[k*64 + cb + cc], acc[cc]);
        }
        #pragma unroll
        for(int cc=0;cc<8;cc++) t1[lane][cb+cc] = fmaxf(acc[cc], 0.f);
    }
    __syncthreads();

    // ---- t2 = relu(t1 @ W2 + b2) -> o_s (reuse)
    {
        int cb = wid*8;
        float acc[8];
        #pragma unroll
        for(int cc=0;cc<8;cc++) acc[cc] = b2[cb+cc];
        for(int k=0;k<64;k++){
            float tv = t1[lane][k];
            #pragma unroll
            for(int cc=0;cc<8;cc++) acc[cc] = fmaf(tv, W2[k*64 + cb + cc], acc[cc]);
        }
        __syncthreads();
        #pragma unroll
        for(int cc=0;cc<8;cc++) o_s[lane][cb+cc] = fmaxf(acc[cc], 0.f);
    }
    __syncthreads();

    // ---- x' = t2 @ W3 + b3 (128 out, 16/lane) -> xs; ms partial
    {
        int cb = wid*16;
        float acc[16];
        #pragma unroll
        for(int cc=0;cc<16;cc++) acc[cc] = b3[cb+cc];
        for(int k=0;k<64;k++){
            float tv = o_s[lane][k];
            #pragma unroll
            for(int cc=0;cc<16;cc++) acc[cc] = fmaf(tv, W3[k*128 + cb + cc], acc[cc]);
        }
        float ms = 0.f;
        #pragma unroll
        for(int cc=0;cc<16;cc++){ xs[lane][cb+cc] = acc[cc]; ms += acc[cc]*acc[cc]; }
        redA[wid][lane] = ms;
    }
    __syncthreads();

    // ---- JKN decision
    if(t < 64){
        int node = base + t; bool u = false;
        if(node < n){
            float ms = 0.f;
            #pragma unroll
            for(int w=0;w<8;w++) ms += redA[w][t];
            u = (layer==0) || (ms > bestMs[node]);
            if(u) bestMs[node] = ms;
        }
        updf[t] = u ? 1 : 0;
    }
    __syncthreads();
    {   // conditional bestF row copy
        int r = t>>3, c0 = (t&7)*16;
        if(updf[r] && base + r < n){
            float* dst = bestF + (size_t)(base+r)*128 + c0;
            #pragma unroll
            for(int q=0;q<16;q++) dst[q] = xs[r][c0+q];
        }
    }
    if(last) return;

    // ---- h_next = x' @ Wn (8/lane) + a_s/a_d for next layer
    {
        int cb = wid*8;
        float acc[8] = {0,0,0,0,0,0,0,0};
        for(int k=0;k<128;k++){
            float xv = xs[lane][k];
            #pragma unroll
            for(int cc=0;cc<8;cc++) acc[cc] = fmaf(xv, Wn[k*64 + cb + cc], acc[cc]);
        }
        float pa=0.f, pd=0.f;
        #pragma unroll
        for(int cc=0;cc<8;cc++){
            t1[lane][cb+cc] = acc[cc];
            pa += acc[cc]*atts[cb+cc];
            pd += acc[cc]*attd[cb+cc];
        }
        redA[wid][lane]=pa; redB[wid][lane]=pd;
    }
    __syncthreads();
    {
        int r = t>>3, c0 = (t&7)*8;
        if(base + r < n){
            float* dst = hn + (size_t)(base+r)*64 + c0;
            #pragma unroll
            for(int q=0;q<8;q++) dst[q] = t1[r][c0+q];
        }
    }
    if(t < 64 && base + t < n){
        float sa=0.f, sd=0.f;
        #pragma unroll
        for(int w=0;w<8;w++){ sa += redA[w][t]; sd += redB[w][t]; }
        asn[base+t] = sa; adn_[base+t] = sd;
    }
}

// ---------------- pooling ----------------

__global__ __launch_bounds__(512) void k_pool1(const float* __restrict__ F,
        const float* __restrict__ A, const float* __restrict__ g1b1,
        const float* __restrict__ w2, const float* __restrict__ g1b2,
        const float* __restrict__ B, const float* __restrict__ g2b1,
        const float* __restrict__ C, const float* __restrict__ g2b2,
        float* __restrict__ h1, float* __restrict__ h2, int n){
    __shared__ float fs[64][129];
    __shared__ float ts[64][65];
    __shared__ float red[4][64];
    int base = blockIdx.x*64, t = threadIdx.x, lane = t & 63;
    int wid = __builtin_amdgcn_readfirstlane(t >> 6);
    {
        int r = t>>3, c0 = (t&7)*16;
        if(base + r < n){
            const float4* srcp = (const float4*)(F + (size_t)(base+r)*128 + c0);
            #pragma unroll
            for(int q=0;q<4;q++){
                float4 v = srcp[q];
                fs[r][c0+q*4+0]=v.x; fs[r][c0+q*4+1]=v.y; fs[r][c0+q*4+2]=v.z; fs[r][c0+q*4+3]=v.w;
            }
        } else {
            #pragma unroll
            for(int q=0;q<16;q++) fs[r][c0+q] = 0.f;
        }
    }
    __syncthreads();
    if(wid < 4){
        int cb = wid*16;
        float acc[16];
        #pragma unroll
        for(int cc=0;cc<16;cc++) acc[cc] = g1b1[cb+cc];
        for(int k=0;k<128;k++){
            float fv = fs[lane][k];
            #pragma unroll
            for(int cc=0;cc<16;cc++) acc[cc] = fmaf(fv, A[k*64 + cb + cc], acc[cc]);
        }
        float pp = 0.f;
        #pragma unroll
        for(int cc=0;cc<16;cc++) pp += fmaxf(acc[cc],0.f)*w2[cb+cc];
        red[wid][lane] = pp;
    } else {
        int cb = (wid-4)*16;
        float acc[16];
        #pragma unroll
        for(int cc=0;cc<16;cc++) acc[cc] = g2b1[cb+cc];
        for(int k=0;k<128;k++){
            float fv = fs[lane][k];
            #pragma unroll
            for(int cc=0;cc<16;cc++) acc[cc] = fmaf(fv, B[k*64 + cb + cc], acc[cc]);
        }
        #pragma unroll
        for(int cc=0;cc<16;cc++) ts[lane][cb+cc] = fmaxf(acc[cc],0.f);
    }
    __syncthreads();
    if(t < 64 && base + t < n)
        h1[base+t] = red[0][t]+red[1][t]+red[2][t]+red[3][t] + g1b2[0];
    {
        int cb = wid*16;
        float acc[16];
        #pragma unroll
        for(int cc=0;cc<16;cc++) acc[cc] = g2b2[cb+cc];
        for(int k=0;k<64;k++){
            float tv = ts[lane][k];
            #pragma unroll
            for(int cc=0;cc<16;cc++) acc[cc] = fmaf(tv, C[k*128 + cb + cc], acc[cc]);
        }
        __syncthreads();
        #pragma unroll
        for(int cc=0;cc<16;cc++) fs[lane][cb+cc] = acc[cc];
    }
    __syncthreads();
    {
        int r = t>>3, c0 = (t&7)*16;
        if(base + r < n){
            float* dst = h2 + (size_t)(base+r)*128 + c0;
            #pragma unroll
            for(int q=0;q<16;q++) dst[q] = fs[r][c0+q];
        }
    }
}

__global__ __launch_bounds__(128) void k_pool2(const float* __restrict__ h1, const float* __restrict__ h2,
                      float* __restrict__ wbuf, float* __restrict__ hg, int n, int G){
    __shared__ float sh[128];
    int g = blockIdx.x, tid = threadIdx.x;
    int start = (g*n + G-1)/G, end = ((g+1)*n + G-1)/G;
    float lm = -1e30f;
    for(int i=start+tid; i<end; i+=128) lm = fmaxf(lm, h1[i]);
    sh[tid]=lm; __syncthreads();
    for(int off=64; off; off>>=1){ if(tid<off) sh[tid]=fmaxf(sh[tid],sh[tid+off]); __syncthreads(); }
    float m = sh[0]; __syncthreads();
    float lsum = 0.f;
    for(int i=start+tid; i<end; i+=128){ float w = expf(h1[i]-m); wbuf[i]=w; lsum+=w; }
    sh[tid]=lsum; __syncthreads();
    for(int off=64; off; off>>=1){ if(tid<off) sh[tid]+=sh[tid+off]; __syncthreads(); }
    float denom = sh[0];
    float a0=0.f,a1=0.f,a2=0.f,a3=0.f;
    int i = start;
    for(; i+3<end; i+=4){
        a0 = fmaf(wbuf[i+0], h2[(size_t)(i+0)*128 + tid], a0);
        a1 = fmaf(wbuf[i+1], h2[(size_t)(i+1)*128 + tid], a1);
        a2 = fmaf(wbuf[i+2], h2[(size_t)(i+2)*128 + tid], a2);
        a3 = fmaf(wbuf[i+3], h2[(size_t)(i+3)*128 + tid], a3);
    }
    for(; i<end; i++) a0 = fmaf(wbuf[i], h2[(size_t)i*128 + tid], a0);
    float acc = (a0+a1)+(a2+a3);
    hg[g*128 + tid] = acc/denom/(float)(end-start);
}

__global__ __launch_bounds__(256) void k_final(const float* __restrict__ hg,
                      const float* __restrict__ pW1, const float* __restrict__ pb1,
                      const float* __restrict__ pW2, const float* __restrict__ pb2,
                      const float* __restrict__ pW3, const float* __restrict__ pb3,
                      float* __restrict__ out, int G){
    int lane = threadIdx.x & 63, wid = threadIdx.x >> 6;
    for(int g = wid; g < G; g += 4){
        const float* r = hg + g*128;
        float t1 = pb1[lane];
        for(int k=0;k<128;k++) t1 += r[k]*pW1[k*64+lane];
        t1 = fmaxf(t1,0.f);
        float t2 = pb2[lane];
        for(int k=0;k<64;k++) t2 += __shfl(t1,k,64)*pW2[k*64+lane];
        t2 = fmaxf(t2,0.f);
        float s = t2*pW3[lane];
        #pragma unroll
        for(int off=32; off; off>>=1) s += __shfl_xor(s,off,64);
        if(lane==0) out[g] = s + pb3[0];
    }
}

extern "C" void kernel_launch(void* const* d_in, const int* in_sizes, int n_in,
                              void* d_out, int out_size, void* d_ws, size_t ws_size,
                              hipStream_t stream){
    const int*   x_idx   = (const int*)  d_in[0];
    const int*   eindex  = (const int*)  d_in[1];
    const int*   eattr   = (const int*)  d_in[2];
    const float* emb     = (const float*)d_in[4];
    const float* conv_W  = (const float*)d_in[5];
    const float* conv_We = (const float*)d_in[6];
    const float* att_src = (const float*)d_in[7];
    const float* att_dst = (const float*)d_in[8];
    const float* att_edg = (const float*)d_in[9];
    const float* conv_b  = (const float*)d_in[10];
    const float* mW1 = (const float*)d_in[11]; const float* mb1 = (const float*)d_in[12];
    const float* mW2 = (const float*)d_in[13]; const float* mb2 = (const float*)d_in[14];
    const float* mW3 = (const float*)d_in[15]; const float* mb3 = (const float*)d_in[16];
    const float* g1W1= (const float*)d_in[17]; const float* g1b1= (const float*)d_in[18];
    const float* g1W2= (const float*)d_in[19]; const float* g1b2= (const float*)d_in[20];
    const float* g2W1= (const float*)d_in[21]; const float* g2b1= (const float*)d_in[22];
    const float* g2W2= (const float*)d_in[23]; const float* g2b2= (const float*)d_in[24];
    const float* pW1 = (const float*)d_in[25]; const float* pb1 = (const float*)d_in[26];
    const float* pW2 = (const float*)d_in[27]; const float* pb2 = (const float*)d_in[28];
    const float* pW3 = (const float*)d_in[29]; const float* pb3 = (const float*)d_in[30];

    const int N = in_sizes[0];
    const int E = in_sizes[2];
    const int G = out_size;
    const int* src = eindex;
    const int* dst = eindex + E;
    const int NT = (N + 63) / 64;
    const int NW = (N + 3) / 4;       // wave-per-node grids

    char* p = (char*)d_ws;
    auto alloc = [&](size_t bytes)->void*{ void* r = (void*)p; p += (bytes + 255) & ~(size_t)255; return r; };
    float* h      = (float*)alloc((size_t)N*64*4);
    float* o      = (float*)alloc((size_t)N*64*4);
    float* bestF  = (float*)alloc((size_t)N*128*4);
    float* h2buf  = (float*)alloc((size_t)N*128*4);
    float* bestMs = (float*)alloc((size_t)N*4);
    float* as_    = (float*)alloc((size_t)N*4);
    float* ad_    = (float*)alloc((size_t)N*4);
    float* ae     = (float*)alloc((size_t)6*E*4);
    float* h1     = (float*)alloc((size_t)N*4);
    float* hg     = (float*)alloc((size_t)G*128*4);
    int*   cnt    = (int*)  alloc((size_t)N*4);
    int*   cnt2   = (int*)  alloc((size_t)N*4);
    int*   rowptr = (int*)  alloc((size_t)(N+1)*4);
    int*   eid    = (int*)  alloc((size_t)E*4);
    int*   csrsrc = (int*)  alloc((size_t)E*4);

    hipMemsetAsync(cnt,  0, (size_t)N*4, stream);
    hipMemsetAsync(cnt2, 0, (size_t)N*4, stream);

    k_count<<<(E+255)/256, 256, 0, stream>>>(dst, cnt, E);
    k_scan<<<1, 1024, 0, stream>>>(cnt, rowptr, N);
    k_scatter<<<(E+255)/256, 256, 0, stream>>>(dst, rowptr, cnt2, eid, E);
    k_sortb<<<NW, 256, 0, stream>>>(rowptr, eid, N);
    k_ae<<<(E+255)/256, 256, 0, stream>>>(eid, src, eattr, emb, conv_We, att_edg, csrsrc, ae, E);
    k_hx<<<NT, 512, 0, stream>>>(x_idx, emb, conv_W, att_src, att_dst, h, as_, ad_, N);

    for(int l=0; l<6; l++){
        int last = (l==5) ? 1 : 0;
        const float* Wn   = last ? conv_W  : conv_W  + (size_t)(l+1)*8192;
        const float* atsn = last ? att_src : att_src + (l+1)*64;
        const float* atdn = last ? att_dst : att_dst + (l+1)*64;
        k_gat<<<NW, 256, 0, stream>>>(h, as_, ad_, ae + (size_t)l*E, rowptr, csrsrc, conv_b + l*64, o, N);
        k_dense<<<NT, 512, 0, stream>>>(o,
            mW1 + (size_t)l*4096, mb1 + l*64, mW2 + (size_t)l*4096, mb2 + l*64,
            mW3 + (size_t)l*8192, mb3 + l*128,
            bestF, bestMs, l,
            Wn, atsn, atdn,
            h, as_, ad_, N, last);
    }

    k_pool1<<<NT, 512, 0, stream>>>(bestF, g1W1, g1b1, g1W2, g1b2, g2W1, g2b1, g2W2, g2b2, h1, h2buf, N);
    k_pool2<<<G, 128, 0, stream>>>(h1, h2buf, bestMs, hg, N, G);
    k_final<<<1, 256, 0, stream>>>(hg, pW1, pb1, pW2, pb2, pW3, pb3, (float*)d_out, G);
}

// Round 4
// 480.854 us; speedup vs baseline: 2.4133x; 1.1233x over previous
//
#include <hip/hip_runtime.h>
#include <math.h>

__device__ __forceinline__ float lrelu(float x){ return x > 0.0f ? x : 0.2f*x; }
__device__ __forceinline__ float bcastf(float v, int l){
    return __int_as_float(__builtin_amdgcn_readlane(__float_as_int(v), l));
}

// ---------------- precompute ----------------

__global__ void k_count(const int* __restrict__ dst, int* __restrict__ cnt, int E){
    int e = blockIdx.x*256 + threadIdx.x;
    if(e < E) atomicAdd(&cnt[dst[e]], 1);
}

// exclusive prefix sum over n counts -> rowptr[0..n] (single block, shuffle scan)
__global__ __launch_bounds__(1024) void k_scan(const int* __restrict__ cnt, int* __restrict__ rowptr, int n){
    __shared__ int ws[16];
    __shared__ int carrysh;
    int t = threadIdx.x, lane = t & 63, wv = t >> 6;
    if(t==0){ carrysh = 0; rowptr[0] = 0; }
    __syncthreads();
    for(int base=0; base<n; base+=1024){
        int i = base + t;
        int v = (i<n) ? cnt[i] : 0;
        int s = v;
        #pragma unroll
        for(int off=1; off<64; off<<=1){ int u = __shfl_up(s, off, 64); if(lane>=off) s += u; }
        if(lane==63) ws[wv] = s;
        __syncthreads();
        if(t < 16){
            int u = ws[t];
            #pragma unroll
            for(int off=1; off<16; off<<=1){ int u2 = __shfl_up(u, off, 16); if(t>=off) u += u2; }
            ws[t] = u;
        }
        __syncthreads();
        int carry = carrysh;
        int wbase = wv ? ws[wv-1] : 0;
        if(i<n) rowptr[i+1] = carry + wbase + s;
        int total = ws[15];
        __syncthreads();
        if(t==0) carrysh = carry + total;
        __syncthreads();
    }
}

__global__ void k_scatter(const int* __restrict__ dst, const int* __restrict__ rowptr,
                          int* __restrict__ cnt2, int* __restrict__ eid, int E){
    int e = blockIdx.x*256 + threadIdx.x;
    if(e >= E) return;
    int d = dst[e];
    int p = rowptr[d] + atomicAdd(&cnt2[d], 1);
    eid[p] = e;
}

// deterministic CSR order: in-register bitonic sort of each node's edge ids (wave per node)
__global__ __launch_bounds__(256) void k_sortb(const int* __restrict__ rowptr, int* __restrict__ eid, int n){
    int node = blockIdx.x*4 + (threadIdx.x>>6);
    if(node >= n) return;
    int lane = threadIdx.x & 63;
    int b = rowptr[node], e = rowptr[node+1];
    int nj = e - b;
    if(nj <= 1) return;
    if(nj <= 64){
        int v = (lane < nj) ? eid[b+lane] : 0x7fffffff;
        for(int k=2; k<=64; k<<=1){
            for(int j=k>>1; j>0; j>>=1){
                int vv = __shfl_xor(v, j, 64);
                bool up = ((lane & k) == 0);
                bool lower = ((lane & j) == 0);
                int mn = min(v,vv), mx = max(v,vv);
                v = (lower == up) ? mn : mx;
            }
        }
        if(lane < nj) eid[b+lane] = v;
    } else if(lane == 0){
        for(int i=b+1; i<e; i++){
            int key = eid[i]; int j = i-1;
            while(j>=b && eid[j] > key){ eid[j+1] = eid[j]; j--; }
            eid[j+1] = key;
        }
    }
}

// per CSR slot: csr_src and a_e for all 6 layers (wvec computed in-block)
__global__ __launch_bounds__(256) void k_ae(const int* __restrict__ eid, const int* __restrict__ src,
                     const int* __restrict__ eattr, const float* __restrict__ emb,
                     const float* __restrict__ We, const float* __restrict__ atte,
                     int* __restrict__ csrsrc, float* __restrict__ ae, int E){
    __shared__ float wv[6*128];
    for(int i=threadIdx.x; i<768; i+=256){
        int l = i>>7, k = i&127;
        const float* w = We + ((size_t)l*128 + k)*64;
        const float* a = atte + l*64;
        float s = 0.f;
        #pragma unroll 8
        for(int c=0;c<64;c++) s += w[c]*a[c];
        wv[i] = s;
    }
    __syncthreads();
    int p = blockIdx.x*256 + threadIdx.x;
    if(p >= E) return;
    int e = eid[p];
    csrsrc[p] = src[e];
    const float4* er = (const float4*)(emb + (size_t)eattr[e]*128);
    float acc[6] = {0,0,0,0,0,0};
    for(int k=0;k<32;k++){
        float4 v = er[k];
        #pragma unroll
        for(int l=0;l<6;l++){
            const float* w = wv + l*128 + k*4;
            acc[l] += v.x*w[0] + v.y*w[1] + v.z*w[2] + v.w*w[3];
        }
    }
    #pragma unroll
    for(int l=0;l<6;l++) ae[(size_t)l*E + p] = acc[l];
}

// ---------------- layer-0 h: gather emb -> x tile -> h = x@W, a_s, a_d ----------------

__global__ __launch_bounds__(512) void k_hx(const int* __restrict__ xidx, const float* __restrict__ emb,
        const float* __restrict__ W, const float* __restrict__ atts, const float* __restrict__ attd,
        float* __restrict__ h, float* __restrict__ as_, float* __restrict__ ad_, int n){
    __shared__ float xs[64][129];
    __shared__ float hs[64][65];
    __shared__ float redA[8][64], redB[8][64];
    int base = blockIdx.x*64;
    int t = threadIdx.x;
    {
        int r = t>>3, c0 = (t&7)*16;
        if(base + r < n){
            const float4* srcp = (const float4*)(emb + (size_t)xidx[base+r]*128 + c0);
            #pragma unroll
            for(int q=0;q<4;q++){
                float4 v = srcp[q];
                xs[r][c0+q*4+0]=v.x; xs[r][c0+q*4+1]=v.y; xs[r][c0+q*4+2]=v.z; xs[r][c0+q*4+3]=v.w;
            }
        } else {
            #pragma unroll
            for(int q=0;q<16;q++) xs[r][c0+q] = 0.f;
        }
    }
    __syncthreads();
    int lane = t & 63;
    int wid = __builtin_amdgcn_readfirstlane(t >> 6);
    int cb = wid*8;
    float acc[8] = {0,0,0,0,0,0,0,0};
    for(int k=0;k<128;k++){
        float xv = xs[lane][k];
        #pragma unroll
        for(int cc=0;cc<8;cc++) acc[cc] = fmaf(xv, W[k*64 + cb + cc], acc[cc]);
    }
    float pa=0.f, pd=0.f;
    #pragma unroll
    for(int cc=0;cc<8;cc++){
        hs[lane][cb+cc] = acc[cc];
        pa += acc[cc]*atts[cb+cc];
        pd += acc[cc]*attd[cb+cc];
    }
    redA[wid][lane]=pa; redB[wid][lane]=pd;
    __syncthreads();
    {
        int r = t>>3, c0 = (t&7)*8;
        if(base + r < n){
            float* dst = h + (size_t)(base+r)*64 + c0;
            #pragma unroll
            for(int q=0;q<8;q++) dst[q] = hs[r][c0+q];
        }
    }
    if(t < 64 && base + t < n){
        float sa=0.f, sd=0.f;
        #pragma unroll
        for(int w=0;w<8;w++){ sa += redA[w][t]; sd += redB[w][t]; }
        as_[base+t] = sa; ad_[base+t] = sd;
    }
}

// ---------------- GAT aggregation: wave per node ----------------

__global__ __launch_bounds__(256) void k_gat(const float* __restrict__ h,
        const float* __restrict__ as_, const float* __restrict__ ad_,
        const float* __restrict__ ae, const int* __restrict__ rowptr,
        const int* __restrict__ csrsrc, const float* __restrict__ bias,
        float* __restrict__ o, int n){
    int node = blockIdx.x*4 + (threadIdx.x>>6);
    if(node >= n) return;
    int lane = threadIdx.x & 63;
    int b = rowptr[node], e = rowptr[node+1];
    float adv = ad_[node];
    float m = -1e30f, d = 0.f, sumae = 0.f;
    float a0=0.f, a1=0.f, a2=0.f, a3=0.f;
    for(int j0=b; j0<e; j0+=64){
        int nj = min(64, e-j0);
        int sj = 0; float aev = 0.f, lg = -1e30f;
        if(lane < nj){
            sj  = csrsrc[j0+lane];
            aev = ae[j0+lane];
            lg  = lrelu(as_[sj] + adv + aev);
        }
        float cm = lg, sa = aev;
        #pragma unroll
        for(int off=32; off; off>>=1){ cm = fmaxf(cm, __shfl_xor(cm,off,64)); sa += __shfl_xor(sa,off,64); }
        sumae += sa;
        float nm = fmaxf(m, cm);
        float w = (lane<nj) ? expf(lg-nm) : 0.f;
        float ws = w;
        #pragma unroll
        for(int off=32; off; off>>=1) ws += __shfl_xor(ws,off,64);
        float scale = (m > -1e29f) ? expf(m-nm) : 0.f;
        d = d*scale + ws;
        a0*=scale; a1*=scale; a2*=scale; a3*=scale;
        int j = 0;
        for(; j+3<nj; j+=4){
            a0 = fmaf(bcastf(w,j+0), h[(size_t)__builtin_amdgcn_readlane(sj,j+0)*64 + lane], a0);
            a1 = fmaf(bcastf(w,j+1), h[(size_t)__builtin_amdgcn_readlane(sj,j+1)*64 + lane], a1);
            a2 = fmaf(bcastf(w,j+2), h[(size_t)__builtin_amdgcn_readlane(sj,j+2)*64 + lane], a2);
            a3 = fmaf(bcastf(w,j+3), h[(size_t)__builtin_amdgcn_readlane(sj,j+3)*64 + lane], a3);
        }
        for(; j<nj; j++)
            a0 = fmaf(bcastf(w,j), h[(size_t)__builtin_amdgcn_readlane(sj,j)*64 + lane], a0);
        m = nm;
    }
    int deg = e - b;
    float ael = sumae / fmaxf((float)deg, 1.f);
    float ls = lrelu(as_[node] + adv + ael);
    float nm = fmaxf(m, ls);
    float scale = (m > -1e29f) ? expf(m-nm) : 0.f;
    float wl = expf(ls-nm);
    d = d*scale + wl;
    float acc = (a0+a1)+(a2+a3);
    acc = acc*scale + wl*h[(size_t)node*64 + lane];
    o[(size_t)node*64 + lane] = acc/d + bias[lane];
}

// ---------------- dense: MLP3 + JKN + next-layer h/a_s/a_d (or fused pooling GEMMs on last) ----------------

__global__ __launch_bounds__(512) void k_dense(
    const float* __restrict__ o,
    const float* __restrict__ W1, const float* __restrict__ b1,
    const float* __restrict__ W2, const float* __restrict__ b2,
    const float* __restrict__ W3, const float* __restrict__ b3,
    float* __restrict__ bestF, float* __restrict__ bestMs, int layer,
    const float* __restrict__ Wn, const float* __restrict__ atts, const float* __restrict__ attd,
    float* __restrict__ hn, float* __restrict__ asn, float* __restrict__ adn_,
    const float* __restrict__ A, const float* __restrict__ g1b1,
    const float* __restrict__ w2, const float* __restrict__ g1b2,
    const float* __restrict__ B, const float* __restrict__ g2b1,
    const float* __restrict__ C, const float* __restrict__ g2b2,
    float* __restrict__ h1, float* __restrict__ h2,
    int n, int last)
{
    __shared__ float o_s[64][65];   // o tile, reused as t2
    __shared__ float t1[64][65];    // mlp hidden, reused as h_next staging / ts
    __shared__ float xs[64][129];   // mlp output (x' tile) / feature tile
    __shared__ float redA[8][64], redB[8][64];
    __shared__ unsigned char updf[64];
    int base = blockIdx.x*64;
    int t = threadIdx.x, lane = t & 63;
    int wid = __builtin_amdgcn_readfirstlane(t >> 6);

    {   // stage o tile (coalesced)
        int r = t>>3, c0 = (t&7)*8;
        if(base + r < n){
            const float4* srcp = (const float4*)(o + (size_t)(base+r)*64 + c0);
            float4 v0 = srcp[0], v1 = srcp[1];
            o_s[r][c0+0]=v0.x; o_s[r][c0+1]=v0.y; o_s[r][c0+2]=v0.z; o_s[r][c0+3]=v0.w;
            o_s[r][c0+4]=v1.x; o_s[r][c0+5]=v1.y; o_s[r][c0+6]=v1.z; o_s[r][c0+7]=v1.w;
        } else {
            #pragma unroll
            for(int q=0;q<8;q++) o_s[r][c0+q] = 0.f;
        }
    }
    __syncthreads();

    // ---- t1 = relu(o @ W1 + b1), 8 cols/lane (uniform W -> s_load)
    {
        int cb = wid*8;
        float acc[8];
        #pragma unroll
        for(int cc=0;cc<8;cc++) acc[cc] = b1[cb+cc];
        for(int k=0;k<64;k++){
            float ov = o_s[lane][k];
            #pragma unroll
            for(int cc=0;cc<8;cc++) acc[cc] = fmaf(ov, W1[k*64 + cb + cc], acc[cc]);
        }
        #pragma unroll
        for(int cc=0;cc<8;cc++) t1[lane][cb+cc] = fmaxf(acc[cc], 0.f);
    }
    __syncthreads();

    // ---- t2 = relu(t1 @ W2 + b2) -> o_s (reuse)
    {
        int cb = wid*8;
        float acc[8];
        #pragma unroll
        for(int cc=0;cc<8;cc++) acc[cc] = b2[cb+cc];
        for(int k=0;k<64;k++){
            float tv = t1[lane][k];
            #pragma unroll
            for(int cc=0;cc<8;cc++) acc[cc] = fmaf(tv, W2[k*64 + cb + cc], acc[cc]);
        }
        __syncthreads();
        #pragma unroll
        for(int cc=0;cc<8;cc++) o_s[lane][cb+cc] = fmaxf(acc[cc], 0.f);
    }
    __syncthreads();

    // ---- x' = t2 @ W3 + b3 (128 out, 16/lane) -> xs; ms partial
    {
        int cb = wid*16;
        float acc[16];
        #pragma unroll
        for(int cc=0;cc<16;cc++) acc[cc] = b3[cb+cc];
        for(int k=0;k<64;k++){
            float tv = o_s[lane][k];
            #pragma unroll
            for(int cc=0;cc<16;cc++) acc[cc] = fmaf(tv, W3[k*128 + cb + cc], acc[cc]);
        }
        float ms = 0.f;
        #pragma unroll
        for(int cc=0;cc<16;cc++){ xs[lane][cb+cc] = acc[cc]; ms += acc[cc]*acc[cc]; }
        redA[wid][lane] = ms;
    }
    __syncthreads();

    // ---- JKN decision
    if(t < 64){
        int node = base + t; bool u = false;
        if(node < n){
            float ms = 0.f;
            #pragma unroll
            for(int w=0;w<8;w++) ms += redA[w][t];
            u = (layer==0) || (ms > bestMs[node]);
            if(u) bestMs[node] = ms;
        }
        updf[t] = u ? 1 : 0;
    }
    __syncthreads();

    if(!last){
        {   // conditional bestF row copy
            int r = t>>3, c0 = (t&7)*16;
            if(updf[r] && base + r < n){
                float* dst = bestF + (size_t)(base+r)*128 + c0;
                #pragma unroll
                for(int q=0;q<16;q++) dst[q] = xs[r][c0+q];
            }
        }
        // ---- h_next = x' @ Wn (8/lane) + a_s/a_d for next layer
        {
            int cb = wid*8;
            float acc[8] = {0,0,0,0,0,0,0,0};
            for(int k=0;k<128;k++){
                float xv = xs[lane][k];
                #pragma unroll
                for(int cc=0;cc<8;cc++) acc[cc] = fmaf(xv, Wn[k*64 + cb + cc], acc[cc]);
            }
            float pa=0.f, pd=0.f;
            #pragma unroll
            for(int cc=0;cc<8;cc++){
                t1[lane][cb+cc] = acc[cc];
                pa += acc[cc]*atts[cb+cc];
                pd += acc[cc]*attd[cb+cc];
            }
            redA[wid][lane]=pa; redB[wid][lane]=pd;
        }
        __syncthreads();
        {
            int r = t>>3, c0 = (t&7)*8;
            if(base + r < n){
                float* dst = hn + (size_t)(base+r)*64 + c0;
                #pragma unroll
                for(int q=0;q<8;q++) dst[q] = t1[r][c0+q];
            }
        }
        if(t < 64 && base + t < n){
            float sa=0.f, sd=0.f;
            #pragma unroll
            for(int w=0;w<8;w++){ sa += redA[w][t]; sd += redB[w][t]; }
            asn[base+t] = sa; adn_[base+t] = sd;
        }
        return;
    }

    // ================= last layer: fused pooling GEMMs =================
    // build feature tile in xs: updated rows already hold x'; others load old bestF
    {
        int r = t>>3, c0 = (t&7)*16;
        if(!updf[r] && base + r < n){
            const float4* srcp = (const float4*)(bestF + (size_t)(base+r)*128 + c0);
            #pragma unroll
            for(int q=0;q<4;q++){
                float4 v = srcp[q];
                xs[r][c0+q*4+0]=v.x; xs[r][c0+q*4+1]=v.y; xs[r][c0+q*4+2]=v.z; xs[r][c0+q*4+3]=v.w;
            }
        }
    }
    __syncthreads();
    if(wid < 4){      // p1 = relu(F@A+b1); partial h1 = dot(p1, w2)
        int cb = wid*16;
        float acc[16];
        #pragma unroll
        for(int cc=0;cc<16;cc++) acc[cc] = g1b1[cb+cc];
        for(int k=0;k<128;k++){
            float fv = xs[lane][k];
            #pragma unroll
            for(int cc=0;cc<16;cc++) acc[cc] = fmaf(fv, A[k*64 + cb + cc], acc[cc]);
        }
        float pp = 0.f;
        #pragma unroll
        for(int cc=0;cc<16;cc++) pp += fmaxf(acc[cc],0.f)*w2[cb+cc];
        redA[wid][lane] = pp;
    } else {          // p2 = relu(F@B+b1') -> ts (t1)
        int cb = (wid-4)*16;
        float acc[16];
        #pragma unroll
        for(int cc=0;cc<16;cc++) acc[cc] = g2b1[cb+cc];
        for(int k=0;k<128;k++){
            float fv = xs[lane][k];
            #pragma unroll
            for(int cc=0;cc<16;cc++) acc[cc] = fmaf(fv, B[k*64 + cb + cc], acc[cc]);
        }
        #pragma unroll
        for(int cc=0;cc<16;cc++) t1[lane][cb+cc] = fmaxf(acc[cc],0.f);
    }
    __syncthreads();
    if(t < 64 && base + t < n)
        h1[base+t] = redA[0][t]+redA[1][t]+redA[2][t]+redA[3][t] + g1b2[0];
    // h2 = ts @ C + b (128 out, 16/lane)
    {
        int cb = wid*16;
        float acc[16];
        #pragma unroll
        for(int cc=0;cc<16;cc++) acc[cc] = g2b2[cb+cc];
        for(int k=0;k<64;k++){
            float tv = t1[lane][k];
            #pragma unroll
            for(int cc=0;cc<16;cc++) acc[cc] = fmaf(tv, C[k*128 + cb + cc], acc[cc]);
        }
        __syncthreads();
        #pragma unroll
        for(int cc=0;cc<16;cc++) xs[lane][cb+cc] = acc[cc];
    }
    __syncthreads();
    {
        int r = t>>3, c0 = (t&7)*16;
        if(base + r < n){
            float* dst = h2 + (size_t)(base+r)*128 + c0;
            #pragma unroll
            for(int q=0;q<16;q++) dst[q] = xs[r][c0+q];
        }
    }
}

// ---------------- pooling softmax + per-graph prediction MLP ----------------

__global__ __launch_bounds__(128) void k_pool2(const float* __restrict__ h1, const float* __restrict__ h2,
                      float* __restrict__ wbuf,
                      const float* __restrict__ pW1, const float* __restrict__ pb1,
                      const float* __restrict__ pW2, const float* __restrict__ pb2,
                      const float* __restrict__ pW3, const float* __restrict__ pb3,
                      float* __restrict__ out, int n, int G){
    __shared__ float sh[128];
    __shared__ float hgrow[128];
    int g = blockIdx.x, tid = threadIdx.x;
    int start = (g*n + G-1)/G, end = ((g+1)*n + G-1)/G;
    float lm = -1e30f;
    for(int i=start+tid; i<end; i+=128) lm = fmaxf(lm, h1[i]);
    sh[tid]=lm; __syncthreads();
    for(int off=64; off; off>>=1){ if(tid<off) sh[tid]=fmaxf(sh[tid],sh[tid+off]); __syncthreads(); }
    float m = sh[0]; __syncthreads();
    float lsum = 0.f;
    for(int i=start+tid; i<end; i+=128){ float w = expf(h1[i]-m); wbuf[i]=w; lsum+=w; }
    sh[tid]=lsum; __syncthreads();
    for(int off=64; off; off>>=1){ if(tid<off) sh[tid]+=sh[tid+off]; __syncthreads(); }
    float denom = sh[0];
    float a0=0.f,a1=0.f,a2=0.f,a3=0.f;
    int i = start;
    for(; i+3<end; i+=4){
        a0 = fmaf(wbuf[i+0], h2[(size_t)(i+0)*128 + tid], a0);
        a1 = fmaf(wbuf[i+1], h2[(size_t)(i+1)*128 + tid], a1);
        a2 = fmaf(wbuf[i+2], h2[(size_t)(i+2)*128 + tid], a2);
        a3 = fmaf(wbuf[i+3], h2[(size_t)(i+3)*128 + tid], a3);
    }
    for(; i<end; i++) a0 = fmaf(wbuf[i], h2[(size_t)i*128 + tid], a0);
    float acc = (a0+a1)+(a2+a3);
    hgrow[tid] = acc/denom/(float)(end-start);
    __syncthreads();
    if(tid < 64){
        float t1v = pb1[tid];
        for(int k=0;k<128;k++) t1v = fmaf(hgrow[k], pW1[k*64+tid], t1v);
        t1v = fmaxf(t1v, 0.f);
        float t2v = pb2[tid];
        for(int k=0;k<64;k++) t2v = fmaf(__shfl(t1v,k,64), pW2[k*64+tid], t2v);
        t2v = fmaxf(t2v, 0.f);
        float s = t2v * pW3[tid];
        #pragma unroll
        for(int off=32; off; off>>=1) s += __shfl_xor(s,off,64);
        if(tid==0) out[g] = s + pb3[0];
    }
}

extern "C" void kernel_launch(void* const* d_in, const int* in_sizes, int n_in,
                              void* d_out, int out_size, void* d_ws, size_t ws_size,
                              hipStream_t stream){
    const int*   x_idx   = (const int*)  d_in[0];
    const int*   eindex  = (const int*)  d_in[1];
    const int*   eattr   = (const int*)  d_in[2];
    const float* emb     = (const float*)d_in[4];
    const float* conv_W  = (const float*)d_in[5];
    const float* conv_We = (const float*)d_in[6];
    const float* att_src = (const float*)d_in[7];
    const float* att_dst = (const float*)d_in[8];
    const float* att_edg = (const float*)d_in[9];
    const float* conv_b  = (const float*)d_in[10];
    const float* mW1 = (const float*)d_in[11]; const float* mb1 = (const float*)d_in[12];
    const float* mW2 = (const float*)d_in[13]; const float* mb2 = (const float*)d_in[14];
    const float* mW3 = (const float*)d_in[15]; const float* mb3 = (const float*)d_in[16];
    const float* g1W1= (const float*)d_in[17]; const float* g1b1= (const float*)d_in[18];
    const float* g1W2= (const float*)d_in[19]; const float* g1b2= (const float*)d_in[20];
    const float* g2W1= (const float*)d_in[21]; const float* g2b1= (const float*)d_in[22];
    const float* g2W2= (const float*)d_in[23]; const float* g2b2= (const float*)d_in[24];
    const float* pW1 = (const float*)d_in[25]; const float* pb1 = (const float*)d_in[26];
    const float* pW2 = (const float*)d_in[27]; const float* pb2 = (const float*)d_in[28];
    const float* pW3 = (const float*)d_in[29]; const float* pb3 = (const float*)d_in[30];

    const int N = in_sizes[0];
    const int E = in_sizes[2];
    const int G = out_size;
    const int* src = eindex;
    const int* dst = eindex + E;
    const int NT = (N + 63) / 64;
    const int NW = (N + 3) / 4;

    char* p = (char*)d_ws;
    auto alloc = [&](size_t bytes)->void*{ void* r = (void*)p; p += (bytes + 255) & ~(size_t)255; return r; };
    float* h      = (float*)alloc((size_t)N*64*4);
    float* o      = (float*)alloc((size_t)N*64*4);
    float* bestF  = (float*)alloc((size_t)N*128*4);
    float* h2buf  = (float*)alloc((size_t)N*128*4);
    float* bestMs = (float*)alloc((size_t)N*4);
    float* as_    = (float*)alloc((size_t)N*4);
    float* ad_    = (float*)alloc((size_t)N*4);
    float* ae     = (float*)alloc((size_t)6*E*4);
    float* h1     = (float*)alloc((size_t)N*4);
    int*   cnt    = (int*)  alloc((size_t)N*4);
    int*   cnt2   = (int*)  alloc((size_t)N*4);
    int*   rowptr = (int*)  alloc((size_t)(N+1)*4);
    int*   eid    = (int*)  alloc((size_t)E*4);
    int*   csrsrc = (int*)  alloc((size_t)E*4);

    hipMemsetAsync(cnt,  0, (size_t)N*4, stream);
    hipMemsetAsync(cnt2, 0, (size_t)N*4, stream);

    k_count<<<(E+255)/256, 256, 0, stream>>>(dst, cnt, E);
    k_scan<<<1, 1024, 0, stream>>>(cnt, rowptr, N);
    k_scatter<<<(E+255)/256, 256, 0, stream>>>(dst, rowptr, cnt2, eid, E);
    k_sortb<<<NW, 256, 0, stream>>>(rowptr, eid, N);
    k_ae<<<(E+255)/256, 256, 0, stream>>>(eid, src, eattr, emb, conv_We, att_edg, csrsrc, ae, E);
    k_hx<<<NT, 512, 0, stream>>>(x_idx, emb, conv_W, att_src, att_dst, h, as_, ad_, N);

    for(int l=0; l<6; l++){
        int last = (l==5) ? 1 : 0;
        const float* Wn   = last ? conv_W  : conv_W  + (size_t)(l+1)*8192;
        const float* atsn = last ? att_src : att_src + (l+1)*64;
        const float* atdn = last ? att_dst : att_dst + (l+1)*64;
        k_gat<<<NW, 256, 0, stream>>>(h, as_, ad_, ae + (size_t)l*E, rowptr, csrsrc, conv_b + l*64, o, N);
        k_dense<<<NT, 512, 0, stream>>>(o,
            mW1 + (size_t)l*4096, mb1 + l*64, mW2 + (size_t)l*4096, mb2 + l*64,
            mW3 + (size_t)l*8192, mb3 + l*128,
            bestF, bestMs, l,
            Wn, atsn, atdn,
            h, as_, ad_,
            g1W1, g1b1, g1W2, g1b2, g2W1, g2b1, g2W2, g2b2,
            h1, h2buf,
            N, last);
    }

    k_pool2<<<G, 128, 0, stream>>>(h1, h2buf, bestMs,
            pW1, pb1, pW2, pb2, pW3, pb3, (float*)d_out, N, G);
}